// Round 3
// baseline (2343.647 us; speedup 1.0000x reference)
//
#include <hip/hip_runtime.h>
#include <cstdint>
#include <cstddef>

#define N_ 4
#define L_ 1024
#define D_ 1024
#define H_ 16
#define HS_ 64
#define M_ (N_*L_)       // 4096 rows
#define DD_ (D_*D_)      // 1048576

__device__ __forceinline__ float sigmoidf_(float x) { return 1.0f / (1.0f + __expf(-x)); }

// ---------------- LayerNorm: one block per row of 1024 ----------------
__global__ __launch_bounds__(256) void ln_kernel(const float* __restrict__ x, float* __restrict__ y,
                                                 const float* __restrict__ sc, const float* __restrict__ bi) {
    int row = blockIdx.x;
    const float* xr = x + (size_t)row * D_;
    float* yr = y + (size_t)row * D_;
    int t = threadIdx.x;
    float4 v = *(const float4*)&xr[t * 4];
    float s = v.x + v.y + v.z + v.w;
    float q = v.x * v.x + v.y * v.y + v.z * v.z + v.w * v.w;
#pragma unroll
    for (int o = 32; o > 0; o >>= 1) { s += __shfl_xor(s, o); q += __shfl_xor(q, o); }
    __shared__ float ss[4], sq[4];
    int w = t >> 6;
    if ((t & 63) == 0) { ss[w] = s; sq[w] = q; }
    __syncthreads();
    s = ss[0] + ss[1] + ss[2] + ss[3];
    q = sq[0] + sq[1] + sq[2] + sq[3];
    float mean = s * (1.0f / D_);
    float var = q * (1.0f / D_) - mean * mean;
    float inv = rsqrtf(var + 1e-5f);
    float4 sv = *(const float4*)&sc[t * 4];
    float4 bv = *(const float4*)&bi[t * 4];
    float4 o4;
    o4.x = (v.x - mean) * inv * sv.x + bv.x;
    o4.y = (v.y - mean) * inv * sv.y + bv.y;
    o4.z = (v.z - mean) * inv * sv.z + bv.z;
    o4.w = (v.w - mean) * inv * sv.w + bv.w;
    *(float4*)&yr[t * 4] = o4;
}

// ------------- per-head projections: one block per (n,l) row -------------
__global__ __launch_bounds__(256) void proj_kernel(const float* __restrict__ qn, const float* __restrict__ vn,
                                                   const float* __restrict__ wq, const float* __restrict__ wk,
                                                   const float* __restrict__ wv,
                                                   float* __restrict__ qh, float* __restrict__ kh,
                                                   float* __restrict__ vh) {
    __shared__ float Wq[64 * 65], Wk[64 * 65], Wv[64 * 65];   // padded +1 to break bank stride
    __shared__ float qrow[D_], vrow[D_];
    int t = threadIdx.x;
    size_t nl = blockIdx.x;
    for (int i = t; i < 4096; i += 256) {
        int d = i >> 6, k = i & 63;
        Wq[d * 65 + k] = wq[i];
        Wk[d * 65 + k] = wk[i];
        Wv[d * 65 + k] = wv[i];
    }
    *(float4*)&qrow[t * 4] = *(const float4*)&qn[nl * D_ + t * 4];
    *(float4*)&vrow[t * 4] = *(const float4*)&vn[nl * D_ + t * 4];
    __syncthreads();
#pragma unroll
    for (int rep = 0; rep < 4; ++rep) {
        int e = rep * 256 + t;
        int h = e >> 6, d = e & 63;
        const float* qr = &qrow[h * 64];
        const float* vr = &vrow[h * 64];
        float aq = 0.f, ak = 0.f, av = 0.f;
#pragma unroll 8
        for (int k = 0; k < 64; ++k) {
            float qv = qr[k], vv = vr[k];
            aq += qv * Wq[d * 65 + k];
            ak += vv * Wk[d * 65 + k];
            av += vv * Wv[d * 65 + k];
        }
        qh[nl * D_ + e] = aq;
        kh[nl * D_ + e] = ak;
        vh[nl * D_ + e] = av;
    }
}

// ------ fused energy + mask + softmax: block = (n,h, 8 q-rows); attn written fp32 ------
__global__ __launch_bounds__(256) void attn_softmax_kernel(const float* __restrict__ qh,
                                                           const float* __restrict__ kh,
                                                           const int* __restrict__ mask,
                                                           float* __restrict__ attn) {
    int t = threadIdx.x;
    int q0 = blockIdx.x * 8;
    int h = blockIdx.y;
    int n = blockIdx.z;
    __shared__ float Qs[8 * 64];
    __shared__ float Ks[64 * 65];
    __shared__ float S[8 * 1024];
    if (t < 128) {
        int q = t >> 4, c = (t & 15) * 4;
        *(float4*)&Qs[q * 64 + c] = *(const float4*)&qh[(((size_t)(n * L_ + q0 + q)) * H_ + h) * HS_ + c];
    }
    int myq = t >> 5;   // 0..7
    int lk = t & 31;    // 0..31
    float* Srow = &S[myq * 1024];
    const float* Qr = &Qs[myq * 64];
    for (int kb = 0; kb < L_; kb += 64) {
        {
            int r = t >> 2, c0 = (t & 3) * 16;
            size_t kbase = (((size_t)(n * L_ + kb + r)) * H_ + h) * HS_ + c0;
#pragma unroll
            for (int i = 0; i < 4; ++i) {
                float4 v = *(const float4*)&kh[kbase + i * 4];
                float* kd = &Ks[r * 65 + c0 + i * 4];
                kd[0] = v.x; kd[1] = v.y; kd[2] = v.z; kd[3] = v.w;
            }
        }
        __syncthreads();
        float s0 = 0.f, s1 = 0.f;
        const float* K0 = &Ks[lk * 65];
        const float* K1 = &Ks[(lk + 32) * 65];
#pragma unroll 16
        for (int d = 0; d < 64; ++d) {
            float qd = Qr[d];
            s0 += qd * K0[d];
            s1 += qd * K1[d];
        }
        Srow[kb + lk] = s0;
        Srow[kb + lk + 32] = s1;
        __syncthreads();
    }
    // softmax over this thread-group's row (32 lanes own row myq; lanes wrote their own entries)
    const float scl = 0.03125f;   // 1/sqrt(1024)
    float sv[32];
    float m = -INFINITY;
#pragma unroll
    for (int j = 0; j < 32; ++j) {
        int k = lk + j * 32;
        float s = Srow[k];
        s = (mask[n * L_ + k] != 0) ? s * scl : -1e20f;
        sv[j] = s;
        m = fmaxf(m, s);
    }
#pragma unroll
    for (int o = 16; o > 0; o >>= 1) m = fmaxf(m, __shfl_xor(m, o));
    float sum = 0.f;
#pragma unroll
    for (int j = 0; j < 32; ++j) { sv[j] = __expf(sv[j] - m); sum += sv[j]; }
#pragma unroll
    for (int o = 16; o > 0; o >>= 1) sum += __shfl_xor(sum, o);
    float inv = 1.0f / sum;
    float* arow = attn + (((size_t)((n * H_ + h) * L_) + q0 + myq)) * L_;
#pragma unroll
    for (int j = 0; j < 32; ++j) arow[lk + j * 32] = sv[j] * inv;
}

// ---------------- PV: o[n,q,h,d] = sum_k attn[n,h,q,k] * vh[n,k,h,d] ----------------
__global__ __launch_bounds__(256) void pv_kernel(const float* __restrict__ attn,
                                                 const float* __restrict__ vh, float* __restrict__ o) {
    __shared__ float Ps[32 * 68];   // [k][q]
    __shared__ float Vs[32 * 68];   // [k][d]
    int t = threadIdx.x;
    int qb = blockIdx.x * 64;
    int h = blockIdx.y;
    int n = blockIdx.z;
    int tm = (t & 15) * 4, tn = (t >> 4) * 4;
    float acc[4][4] = {};
    const float* abase = attn + ((size_t)((n * H_ + h) * L_) + qb) * L_;
    for (int kb = 0; kb < L_; kb += 32) {
        {
            int q = t >> 2, k0 = (t & 3) * 8;
            const float* ps = &abase[(size_t)q * L_ + kb + k0];
            float4 u0 = *(const float4*)ps;
            float4 u1 = *(const float4*)(ps + 4);
            Ps[(k0 + 0) * 68 + q] = u0.x;
            Ps[(k0 + 1) * 68 + q] = u0.y;
            Ps[(k0 + 2) * 68 + q] = u0.z;
            Ps[(k0 + 3) * 68 + q] = u0.w;
            Ps[(k0 + 4) * 68 + q] = u1.x;
            Ps[(k0 + 5) * 68 + q] = u1.y;
            Ps[(k0 + 6) * 68 + q] = u1.z;
            Ps[(k0 + 7) * 68 + q] = u1.w;
        }
        {
            int k = t >> 3, d0 = (t & 7) * 8;
            const float* vb = &vh[(((size_t)(n * L_ + kb + k)) * H_ + h) * HS_ + d0];
            float4 v0 = *(const float4*)vb;
            float4 v1 = *(const float4*)(vb + 4);
            *(float4*)&Vs[k * 68 + d0] = v0;
            *(float4*)&Vs[k * 68 + d0 + 4] = v1;
        }
        __syncthreads();
#pragma unroll 8
        for (int k = 0; k < 32; ++k) {
            float4 a = *(const float4*)&Ps[k * 68 + tm];
            float4 b = *(const float4*)&Vs[k * 68 + tn];
            float av[4] = { a.x, a.y, a.z, a.w };
            float bv[4] = { b.x, b.y, b.z, b.w };
#pragma unroll
            for (int i = 0; i < 4; ++i)
#pragma unroll
                for (int j = 0; j < 4; ++j) acc[i][j] += av[i] * bv[j];
        }
        __syncthreads();
    }
#pragma unroll
    for (int i = 0; i < 4; ++i) {
        float4 w = { acc[i][0], acc[i][1], acc[i][2], acc[i][3] };
        *(float4*)&o[(((size_t)(n * L_ + qb + tm + i)) * H_ + h) * HS_ + tn] = w;
    }
}

// ---------- generic fp32 GEMM: C[M,N] (+)= A[M,K] @ B[N,K]^T (+bias) (ReLU) ----------
// 128x64 tile, BK=16, 256 threads, 8x4 per thread
__global__ __launch_bounds__(256) void gemm_bt_kernel(const float* __restrict__ A, const float* __restrict__ B,
                                                      const float* __restrict__ bias, float* __restrict__ C,
                                                      int M, int N, int K, int accum, int relu) {
    __shared__ float As[16 * 132];   // [k][m0..127]
    __shared__ float Bs[16 * 68];    // [k][n0..63]
    int t = threadIdx.x;
    int m0 = blockIdx.x * 128, n0 = blockIdx.y * 64;
    int lr = t >> 2, lc = (t & 3) * 4;
    const float* Ab = A + (size_t)(m0 + lr) * K + lc;
    const float* Bb = B + (size_t)(n0 + lr) * K + lc;
    int tm = (t & 15) * 8, tn = (t >> 4) * 4;
    float acc[8][4] = {};
    for (int kk = 0; kk < K; kk += 16) {
        float4 a0 = *(const float4*)&Ab[kk];
        float4 a1 = *(const float4*)&Ab[kk + (size_t)64 * K];
        float4 b0 = *(const float4*)&Bb[kk];
        __syncthreads();
        As[(lc + 0) * 132 + lr] = a0.x;
        As[(lc + 1) * 132 + lr] = a0.y;
        As[(lc + 2) * 132 + lr] = a0.z;
        As[(lc + 3) * 132 + lr] = a0.w;
        As[(lc + 0) * 132 + lr + 64] = a1.x;
        As[(lc + 1) * 132 + lr + 64] = a1.y;
        As[(lc + 2) * 132 + lr + 64] = a1.z;
        As[(lc + 3) * 132 + lr + 64] = a1.w;
        Bs[(lc + 0) * 68 + lr] = b0.x;
        Bs[(lc + 1) * 68 + lr] = b0.y;
        Bs[(lc + 2) * 68 + lr] = b0.z;
        Bs[(lc + 3) * 68 + lr] = b0.w;
        __syncthreads();
#pragma unroll
        for (int k = 0; k < 16; ++k) {
            float4 av0 = *(const float4*)&As[k * 132 + tm];
            float4 av1 = *(const float4*)&As[k * 132 + tm + 4];
            float4 bv = *(const float4*)&Bs[k * 68 + tn];
            float a8[8] = { av0.x, av0.y, av0.z, av0.w, av1.x, av1.y, av1.z, av1.w };
            float b4[4] = { bv.x, bv.y, bv.z, bv.w };
#pragma unroll
            for (int i = 0; i < 8; ++i)
#pragma unroll
                for (int j = 0; j < 4; ++j) acc[i][j] += a8[i] * b4[j];
        }
    }
    float4 bb = { 0.f, 0.f, 0.f, 0.f };
    if (bias) bb = *(const float4*)&bias[n0 + tn];
#pragma unroll
    for (int i = 0; i < 8; ++i) {
        size_t off = (size_t)(m0 + tm + i) * N + n0 + tn;
        float4 c = { acc[i][0], acc[i][1], acc[i][2], acc[i][3] };
        if (accum) {
            float4 p = *(const float4*)&C[off];
            c.x += p.x; c.y += p.y; c.z += p.z; c.w += p.w;
        }
        c.x += bb.x; c.y += bb.y; c.z += bb.z; c.w += bb.w;
        if (relu) {
            c.x = fmaxf(c.x, 0.f); c.y = fmaxf(c.y, 0.f);
            c.z = fmaxf(c.z, 0.f); c.w = fmaxf(c.w, 0.f);
        }
        *(float4*)&C[off] = c;
    }
}

// ---------- GRU gate elementwise: r=sig(rp); t=r*x (into rp); z=sig(zp-bg) (into zp) ----------
__global__ __launch_bounds__(256) void gate_rz_t_kernel(float* __restrict__ rp, float* __restrict__ zp,
                                                        const float* __restrict__ x, const float* __restrict__ bg) {
    int i = blockIdx.x * 256 + threadIdx.x;
    float4 r4 = ((const float4*)rp)[i];
    float4 z4 = ((const float4*)zp)[i];
    float4 x4 = ((const float4*)x)[i];
    float4 b4 = *(const float4*)&bg[(i & 255) * 4];
    float4 t4, zz;
    t4.x = sigmoidf_(r4.x) * x4.x; zz.x = sigmoidf_(z4.x - b4.x);
    t4.y = sigmoidf_(r4.y) * x4.y; zz.y = sigmoidf_(z4.y - b4.y);
    t4.z = sigmoidf_(r4.z) * x4.z; zz.z = sigmoidf_(z4.z - b4.z);
    t4.w = sigmoidf_(r4.w) * x4.w; zz.w = sigmoidf_(z4.w - b4.w);
    ((float4*)rp)[i] = t4;
    ((float4*)zp)[i] = zz;
}

// ---------- GRU gate output: out = (1-z)*x + z*tanh(hp), fp32 out ----------
__global__ __launch_bounds__(256) void gate_out_kernel(const float* __restrict__ hp, const float* __restrict__ z,
                                                       const float* __restrict__ x, float* __restrict__ outf) {
    int i = blockIdx.x * 256 + threadIdx.x;
    float4 h4 = ((const float4*)hp)[i];
    float4 z4 = ((const float4*)z)[i];
    float4 x4 = ((const float4*)x)[i];
    float4 o;
    o.x = (1.f - z4.x) * x4.x + z4.x * tanhf(h4.x);
    o.y = (1.f - z4.y) * x4.y + z4.y * tanhf(h4.y);
    o.z = (1.f - z4.z) * x4.z + z4.z * tanhf(h4.z);
    o.w = (1.f - z4.w) * x4.w + z4.w * tanhf(h4.w);
    ((float4*)outf)[i] = o;
}

extern "C" void kernel_launch(void* const* d_in, const int* in_sizes, int n_in,
                              void* d_out, int out_size, void* d_ws, size_t ws_size,
                              hipStream_t stream) {
    const float* value = (const float*)d_in[0];
    // d_in[1] = key (unused: reference sets k_ = normed value)
    const float* query = (const float*)d_in[2];
    const int* mask = (const int*)d_in[3];
    const float* wq = (const float*)d_in[4];
    const float* wk = (const float*)d_in[5];
    const float* wv = (const float*)d_in[6];
    const float* w_out = (const float*)d_in[7];
    const float* b_out = (const float*)d_in[8];
    const float* fc_w = (const float*)d_in[9];
    const float* fc_b = (const float*)d_in[10];
    const float* ln1_s = (const float*)d_in[11];
    const float* ln1_b = (const float*)d_in[12];
    const float* lnkv_s = (const float*)d_in[13];
    const float* lnkv_b = (const float*)d_in[14];
    const float* ln2_s = (const float*)d_in[15];
    const float* ln2_b = (const float*)d_in[16];
    const float* g1_W = (const float*)d_in[17];
    const float* g1_U = (const float*)d_in[18];
    const float* g1_bg = (const float*)d_in[19];
    const float* g2_W = (const float*)d_in[20];
    const float* g2_U = (const float*)d_in[21];
    const float* g2_bg = (const float*)d_in[22];

    float* B0 = (float*)d_ws;
    float* B1 = B0 + (size_t)M_ * D_;
    float* B2 = B1 + (size_t)M_ * D_;
    float* B3 = B2 + (size_t)M_ * D_;
    float* B4 = B3 + (size_t)M_ * D_;

    float* out_f = (float*)d_out;                       // [N,L,D] fp32
    float* attn_f = out_f + (size_t)M_ * D_;            // [N,H,L,L] fp32

    const int EW_GRID = (M_ * D_ / 4) / 256;            // 4096
    dim3 gemm_grid(M_ / 128, D_ / 64);

    auto gemm = [&](const float* A, const float* B, const float* bias, float* C, int accum, int relu) {
        gemm_bt_kernel<<<gemm_grid, 256, 0, stream>>>(A, B, bias, C, M_, D_, D_, accum, relu);
    };

    // pre-LN
    ln_kernel<<<M_, 256, 0, stream>>>(query, B0, ln1_s, ln1_b);
    ln_kernel<<<M_, 256, 0, stream>>>(value, B1, lnkv_s, lnkv_b);
    // per-head projections (k_ = v_)
    proj_kernel<<<M_, 256, 0, stream>>>(B0, B1, wq, wk, wv, B2, B3, B4);
    // fused energy + mask + softmax -> fp32 attn (output 1)
    attn_softmax_kernel<<<dim3(L_ / 8, H_, N_), 256, 0, stream>>>(B2, B3, mask, attn_f);
    // PV -> o (fp32, [N,L,H,hs] == [N,L,D])
    pv_kernel<<<dim3(L_ / 64, H_, N_), 256, 0, stream>>>(attn_f, B4, B0);
    // o_proj = o @ w_out.T + b_out
    gemm(B0, w_out, b_out, B1, 0, 0);

    // GRU gate 1: x = query, y = B1
    gemm(B1, g1_W, nullptr, B2, 0, 0);
    gemm(query, g1_U, nullptr, B2, 1, 0);
    gemm(B1, g1_W + DD_, nullptr, B3, 0, 0);
    gemm(query, g1_U + DD_, nullptr, B3, 1, 0);
    gemm(B1, g1_W + 2 * DD_, nullptr, B4, 0, 0);
    gate_rz_t_kernel<<<EW_GRID, 256, 0, stream>>>(B2, B3, query, g1_bg);
    gemm(B2, g1_U + 2 * DD_, nullptr, B4, 1, 0);
    gate_out_kernel<<<EW_GRID, 256, 0, stream>>>(B4, B3, query, B0);   // h -> B0

    // LN2 + FC
    ln_kernel<<<M_, 256, 0, stream>>>(B0, B2, ln2_s, ln2_b);
    gemm(B2, fc_w, fc_b, B1, 0, 1);                                    // f -> B1 (ReLU)

    // GRU gate 2: x = B0 (h), y = B1 (f)
    gemm(B1, g2_W, nullptr, B2, 0, 0);
    gemm(B0, g2_U, nullptr, B2, 1, 0);
    gemm(B1, g2_W + DD_, nullptr, B3, 0, 0);
    gemm(B0, g2_U + DD_, nullptr, B3, 1, 0);
    gemm(B1, g2_W + 2 * DD_, nullptr, B4, 0, 0);
    gate_rz_t_kernel<<<EW_GRID, 256, 0, stream>>>(B2, B3, B0, g2_bg);
    gemm(B2, g2_U + 2 * DD_, nullptr, B4, 1, 0);
    gate_out_kernel<<<EW_GRID, 256, 0, stream>>>(B4, B3, B0, out_f);   // out (fp32)
}

// Round 4
// 1238.271 us; speedup vs baseline: 1.8927x; 1.8927x over previous
//
#include <hip/hip_runtime.h>
#include <cstdint>
#include <cstddef>

#define N_ 4
#define L_ 1024
#define D_ 1024
#define H_ 16
#define HS_ 64
#define M_ (N_*L_)       // 4096 rows
#define DD_ (D_*D_)      // 1048576

typedef __bf16 b16x8 __attribute__((ext_vector_type(8)));
typedef float f32x4 __attribute__((ext_vector_type(4)));

__device__ __forceinline__ float sigmoidf_(float x) { return 1.0f / (1.0f + __expf(-x)); }
__device__ __forceinline__ unsigned short f2bf(float f) {
    union { float f; uint32_t u; } c; c.f = f;
    uint32_t u = c.u;
    u += 0x7fffu + ((u >> 16) & 1u);   // RNE
    return (unsigned short)(u >> 16);
}

// ---------------- LayerNorm: one block per row of 1024 ----------------
__global__ __launch_bounds__(256) void ln_kernel(const float* __restrict__ x, float* __restrict__ y,
                                                 const float* __restrict__ sc, const float* __restrict__ bi) {
    int row = blockIdx.x;
    const float* xr = x + (size_t)row * D_;
    float* yr = y + (size_t)row * D_;
    int t = threadIdx.x;
    float4 v = *(const float4*)&xr[t * 4];
    float s = v.x + v.y + v.z + v.w;
    float q = v.x * v.x + v.y * v.y + v.z * v.z + v.w * v.w;
#pragma unroll
    for (int o = 32; o > 0; o >>= 1) { s += __shfl_xor(s, o); q += __shfl_xor(q, o); }
    __shared__ float ss[4], sq[4];
    int w = t >> 6;
    if ((t & 63) == 0) { ss[w] = s; sq[w] = q; }
    __syncthreads();
    s = ss[0] + ss[1] + ss[2] + ss[3];
    q = sq[0] + sq[1] + sq[2] + sq[3];
    float mean = s * (1.0f / D_);
    float var = q * (1.0f / D_) - mean * mean;
    float inv = rsqrtf(var + 1e-5f);
    float4 sv = *(const float4*)&sc[t * 4];
    float4 bv = *(const float4*)&bi[t * 4];
    float4 o4;
    o4.x = (v.x - mean) * inv * sv.x + bv.x;
    o4.y = (v.y - mean) * inv * sv.y + bv.y;
    o4.z = (v.z - mean) * inv * sv.z + bv.z;
    o4.w = (v.w - mean) * inv * sv.w + bv.w;
    *(float4*)&yr[t * 4] = o4;
}

// ------------- per-head projections: one block per (n,l) row -------------
__global__ __launch_bounds__(256) void proj_kernel(const float* __restrict__ qn, const float* __restrict__ vn,
                                                   const float* __restrict__ wq, const float* __restrict__ wk,
                                                   const float* __restrict__ wv,
                                                   float* __restrict__ qh, float* __restrict__ kh,
                                                   float* __restrict__ vh) {
    __shared__ float Wq[64 * 65], Wk[64 * 65], Wv[64 * 65];
    __shared__ float qrow[D_], vrow[D_];
    int t = threadIdx.x;
    size_t nl = blockIdx.x;
    for (int i = t; i < 4096; i += 256) {
        int d = i >> 6, k = i & 63;
        Wq[d * 65 + k] = wq[i];
        Wk[d * 65 + k] = wk[i];
        Wv[d * 65 + k] = wv[i];
    }
    *(float4*)&qrow[t * 4] = *(const float4*)&qn[nl * D_ + t * 4];
    *(float4*)&vrow[t * 4] = *(const float4*)&vn[nl * D_ + t * 4];
    __syncthreads();
#pragma unroll
    for (int rep = 0; rep < 4; ++rep) {
        int e = rep * 256 + t;
        int h = e >> 6, d = e & 63;
        const float* qr = &qrow[h * 64];
        const float* vr = &vrow[h * 64];
        float aq = 0.f, ak = 0.f, av = 0.f;
#pragma unroll 8
        for (int k = 0; k < 64; ++k) {
            float qv = qr[k], vv = vr[k];
            aq += qv * Wq[d * 65 + k];
            ak += vv * Wk[d * 65 + k];
            av += vv * Wv[d * 65 + k];
        }
        qh[nl * D_ + e] = aq;
        kh[nl * D_ + e] = ak;
        vh[nl * D_ + e] = av;
    }
}

// ------ fused energy + mask + softmax; scores accumulate in registers ------
__global__ __launch_bounds__(256) void attn_softmax_kernel(const float* __restrict__ qh,
                                                           const float* __restrict__ kh,
                                                           const int* __restrict__ mask,
                                                           float* __restrict__ attn) {
    int t = threadIdx.x;
    int q0 = blockIdx.x * 8;
    int h = blockIdx.y;
    int n = blockIdx.z;
    __shared__ float Qs[8 * 64];
    __shared__ float Ks[64 * 68];
    if (t < 128) {
        int q = t >> 4, c = (t & 15) * 4;
        *(float4*)&Qs[q * 64 + c] = *(const float4*)&qh[(((size_t)(n * L_ + q0 + q)) * H_ + h) * HS_ + c];
    }
    int myq = t >> 5;   // 0..7
    int lk = t & 31;    // 0..31
    const float* Qr = &Qs[myq * 64];
    int sr_ = t >> 2, sc_ = (t & 3) * 16;
    float sv[32];
#pragma unroll
    for (int kbi = 0; kbi < 16; ++kbi) {
        int kb = kbi * 64;
        {
            size_t kbase = (((size_t)(n * L_ + kb + sr_)) * H_ + h) * HS_ + sc_;
#pragma unroll
            for (int i = 0; i < 4; ++i) {
                float4 v = *(const float4*)&kh[kbase + i * 4];
                *(float4*)&Ks[sr_ * 68 + sc_ + i * 4] = v;
            }
        }
        __syncthreads();
        float s0 = 0.f, s1 = 0.f;
        const float* K0 = &Ks[lk * 68];
        const float* K1 = &Ks[(lk + 32) * 68];
#pragma unroll
        for (int d = 0; d < 64; d += 4) {
            float4 q4 = *(const float4*)&Qr[d];
            float4 a4 = *(const float4*)&K0[d];
            float4 b4 = *(const float4*)&K1[d];
            s0 += q4.x * a4.x + q4.y * a4.y + q4.z * a4.z + q4.w * a4.w;
            s1 += q4.x * b4.x + q4.y * b4.y + q4.z * b4.z + q4.w * b4.w;
        }
        sv[2 * kbi] = s0;
        sv[2 * kbi + 1] = s1;
        __syncthreads();
    }
    // softmax: lane lk owns k = lk + j*32 for row (q0+myq)
    const float scl = 0.03125f;   // 1/sqrt(1024)
    float m = -INFINITY;
#pragma unroll
    for (int j = 0; j < 32; ++j) {
        int k = lk + j * 32;
        float s = sv[j];
        s = (mask[n * L_ + k] != 0) ? s * scl : -1e20f;
        sv[j] = s;
        m = fmaxf(m, s);
    }
#pragma unroll
    for (int o = 16; o > 0; o >>= 1) m = fmaxf(m, __shfl_xor(m, o));
    float sum = 0.f;
#pragma unroll
    for (int j = 0; j < 32; ++j) { sv[j] = __expf(sv[j] - m); sum += sv[j]; }
#pragma unroll
    for (int o = 16; o > 0; o >>= 1) sum += __shfl_xor(sum, o);
    float inv = 1.0f / sum;
    float* arow = attn + (((size_t)((n * H_ + h) * L_) + q0 + myq)) * L_;
#pragma unroll
    for (int j = 0; j < 32; ++j) arow[lk + j * 32] = sv[j] * inv;
}

// ---------------- PV: o[n,q,h,d] = sum_k attn[n,h,q,k] * vh[n,k,h,d] ----------------
__global__ __launch_bounds__(256) void pv_kernel(const float* __restrict__ attn,
                                                 const float* __restrict__ vh, float* __restrict__ o) {
    __shared__ float Ps[32 * 68];   // [k][q]
    __shared__ float Vs[32 * 68];   // [k][d]
    int t = threadIdx.x;
    int qb = blockIdx.x * 64;
    int h = blockIdx.y;
    int n = blockIdx.z;
    int tm = (t & 15) * 4, tn = (t >> 4) * 4;
    float acc[4][4] = {};
    const float* abase = attn + ((size_t)((n * H_ + h) * L_) + qb) * L_;
    for (int kb = 0; kb < L_; kb += 32) {
        {
            int q = t >> 2, k0 = (t & 3) * 8;
            const float* ps = &abase[(size_t)q * L_ + kb + k0];
            float4 u0 = *(const float4*)ps;
            float4 u1 = *(const float4*)(ps + 4);
            Ps[(k0 + 0) * 68 + q] = u0.x;
            Ps[(k0 + 1) * 68 + q] = u0.y;
            Ps[(k0 + 2) * 68 + q] = u0.z;
            Ps[(k0 + 3) * 68 + q] = u0.w;
            Ps[(k0 + 4) * 68 + q] = u1.x;
            Ps[(k0 + 5) * 68 + q] = u1.y;
            Ps[(k0 + 6) * 68 + q] = u1.z;
            Ps[(k0 + 7) * 68 + q] = u1.w;
        }
        {
            int k = t >> 3, d0 = (t & 7) * 8;
            const float* vb = &vh[(((size_t)(n * L_ + kb + k)) * H_ + h) * HS_ + d0];
            float4 v0 = *(const float4*)vb;
            float4 v1 = *(const float4*)(vb + 4);
            *(float4*)&Vs[k * 68 + d0] = v0;
            *(float4*)&Vs[k * 68 + d0 + 4] = v1;
        }
        __syncthreads();
#pragma unroll 8
        for (int k = 0; k < 32; ++k) {
            float4 a = *(const float4*)&Ps[k * 68 + tm];
            float4 b = *(const float4*)&Vs[k * 68 + tn];
            float av[4] = { a.x, a.y, a.z, a.w };
            float bv[4] = { b.x, b.y, b.z, b.w };
#pragma unroll
            for (int i = 0; i < 4; ++i)
#pragma unroll
                for (int j = 0; j < 4; ++j) acc[i][j] += av[i] * bv[j];
        }
        __syncthreads();
    }
#pragma unroll
    for (int i = 0; i < 4; ++i) {
        float4 w = { acc[i][0], acc[i][1], acc[i][2], acc[i][3] };
        *(float4*)&o[(((size_t)(n * L_ + qb + tm + i)) * H_ + h) * HS_ + tn] = w;
    }
}

// ---------- MFMA GEMM: C[M,N] (+)= A[M,K] @ B[N,K]^T (+bias)(ReLU), fp32 io, bf16 compute ----------
// 128x128 tile, 4 waves (2x2 of 64x64), BK=32, in-kernel fp32->bf16 RNE conversion in staging.
#define LDQ 40   // LDS row stride in bf16 elems (80 B: 16B-aligned, ~2-way banks)
__global__ __launch_bounds__(256) void gemm_mfma_kernel(const float* __restrict__ A,
                                                        const float* __restrict__ B,
                                                        const float* __restrict__ bias,
                                                        float* __restrict__ C,
                                                        int M, int N, int K, int accum, int relu) {
    __shared__ unsigned short As[128 * LDQ];
    __shared__ unsigned short Bs[128 * LDQ];
    int t = threadIdx.x;
    int l = t & 63, w = t >> 6;
    int wr = w >> 1, wc = w & 1;
    int m0 = blockIdx.x * 128, n0 = blockIdx.y * 128;
    int sr = t >> 1, sc = (t & 1) * 16;           // staging: row, 16-float chunk
    const float* Ag = A + (size_t)(m0 + sr) * K + sc;
    const float* Bg = B + (size_t)(n0 + sr) * K + sc;
    int fr = l & 15, fq = l >> 4;                 // fragment row/col, k-group

    f32x4 acc[4][4];
#pragma unroll
    for (int i = 0; i < 4; ++i)
#pragma unroll
        for (int j = 0; j < 4; ++j) acc[i][j] = (f32x4){0.f, 0.f, 0.f, 0.f};

    float ra[16], rb[16];
#pragma unroll
    for (int i = 0; i < 4; ++i) {
        *(float4*)&ra[i * 4] = *(const float4*)&Ag[i * 4];
        *(float4*)&rb[i * 4] = *(const float4*)&Bg[i * 4];
    }
    for (int kk = 0; kk < K; kk += 32) {
        __syncthreads();
        unsigned short ta[16], tb[16];
#pragma unroll
        for (int i = 0; i < 16; ++i) { ta[i] = f2bf(ra[i]); tb[i] = f2bf(rb[i]); }
#pragma unroll
        for (int i = 0; i < 4; ++i) {
            *(ushort4*)&As[sr * LDQ + sc + i * 4] = *(ushort4*)&ta[i * 4];
            *(ushort4*)&Bs[sr * LDQ + sc + i * 4] = *(ushort4*)&tb[i * 4];
        }
        if (kk + 32 < K) {
#pragma unroll
            for (int i = 0; i < 4; ++i) {
                *(float4*)&ra[i * 4] = *(const float4*)&Ag[kk + 32 + i * 4];
                *(float4*)&rb[i * 4] = *(const float4*)&Bg[kk + 32 + i * 4];
            }
        }
        __syncthreads();
        b16x8 af[4], bfr[4];
#pragma unroll
        for (int i = 0; i < 4; ++i) {
            af[i]  = *(const b16x8*)&As[(wr * 64 + i * 16 + fr) * LDQ + fq * 8];
            bfr[i] = *(const b16x8*)&Bs[(wc * 64 + i * 16 + fr) * LDQ + fq * 8];
        }
#pragma unroll
        for (int i = 0; i < 4; ++i)
#pragma unroll
            for (int j = 0; j < 4; ++j)
                acc[i][j] = __builtin_amdgcn_mfma_f32_16x16x32_bf16(af[i], bfr[j], acc[i][j], 0, 0, 0);
    }
#pragma unroll
    for (int i = 0; i < 4; ++i) {
#pragma unroll
        for (int j = 0; j < 4; ++j) {
            int row = m0 + wr * 64 + i * 16 + fq * 4;
            int col = n0 + wc * 64 + j * 16 + fr;
            float bv = bias ? bias[col] : 0.f;
#pragma unroll
            for (int r = 0; r < 4; ++r) {
                size_t off = (size_t)(row + r) * N + col;
                float v = acc[i][j][r] + bv;
                if (accum) v += C[off];
                if (relu) v = fmaxf(v, 0.f);
                C[off] = v;
            }
        }
    }
}

// ---------- GRU gate elementwise: r=sig(rp); t=r*x (into rp); z=sig(zp-bg) (into zp) ----------
__global__ __launch_bounds__(256) void gate_rz_t_kernel(float* __restrict__ rp, float* __restrict__ zp,
                                                        const float* __restrict__ x, const float* __restrict__ bg) {
    int i = blockIdx.x * 256 + threadIdx.x;
    float4 r4 = ((const float4*)rp)[i];
    float4 z4 = ((const float4*)zp)[i];
    float4 x4 = ((const float4*)x)[i];
    float4 b4 = *(const float4*)&bg[(i & 255) * 4];
    float4 t4, zz;
    t4.x = sigmoidf_(r4.x) * x4.x; zz.x = sigmoidf_(z4.x - b4.x);
    t4.y = sigmoidf_(r4.y) * x4.y; zz.y = sigmoidf_(z4.y - b4.y);
    t4.z = sigmoidf_(r4.z) * x4.z; zz.z = sigmoidf_(z4.z - b4.z);
    t4.w = sigmoidf_(r4.w) * x4.w; zz.w = sigmoidf_(z4.w - b4.w);
    ((float4*)rp)[i] = t4;
    ((float4*)zp)[i] = zz;
}

// ---------- GRU gate output: out = (1-z)*x + z*tanh(hp), fp32 out ----------
__global__ __launch_bounds__(256) void gate_out_kernel(const float* __restrict__ hp, const float* __restrict__ z,
                                                       const float* __restrict__ x, float* __restrict__ outf) {
    int i = blockIdx.x * 256 + threadIdx.x;
    float4 h4 = ((const float4*)hp)[i];
    float4 z4 = ((const float4*)z)[i];
    float4 x4 = ((const float4*)x)[i];
    float4 o;
    o.x = (1.f - z4.x) * x4.x + z4.x * tanhf(h4.x);
    o.y = (1.f - z4.y) * x4.y + z4.y * tanhf(h4.y);
    o.z = (1.f - z4.z) * x4.z + z4.z * tanhf(h4.z);
    o.w = (1.f - z4.w) * x4.w + z4.w * tanhf(h4.w);
    ((float4*)outf)[i] = o;
}

extern "C" void kernel_launch(void* const* d_in, const int* in_sizes, int n_in,
                              void* d_out, int out_size, void* d_ws, size_t ws_size,
                              hipStream_t stream) {
    const float* value = (const float*)d_in[0];
    // d_in[1] = key (unused: reference sets k_ = normed value)
    const float* query = (const float*)d_in[2];
    const int* mask = (const int*)d_in[3];
    const float* wq = (const float*)d_in[4];
    const float* wk = (const float*)d_in[5];
    const float* wv = (const float*)d_in[6];
    const float* w_out = (const float*)d_in[7];
    const float* b_out = (const float*)d_in[8];
    const float* fc_w = (const float*)d_in[9];
    const float* fc_b = (const float*)d_in[10];
    const float* ln1_s = (const float*)d_in[11];
    const float* ln1_b = (const float*)d_in[12];
    const float* lnkv_s = (const float*)d_in[13];
    const float* lnkv_b = (const float*)d_in[14];
    const float* ln2_s = (const float*)d_in[15];
    const float* ln2_b = (const float*)d_in[16];
    const float* g1_W = (const float*)d_in[17];
    const float* g1_U = (const float*)d_in[18];
    const float* g1_bg = (const float*)d_in[19];
    const float* g2_W = (const float*)d_in[20];
    const float* g2_U = (const float*)d_in[21];
    const float* g2_bg = (const float*)d_in[22];

    float* B0 = (float*)d_ws;
    float* B1 = B0 + (size_t)M_ * D_;
    float* B2 = B1 + (size_t)M_ * D_;
    float* B3 = B2 + (size_t)M_ * D_;
    float* B4 = B3 + (size_t)M_ * D_;

    float* out_f = (float*)d_out;                       // [N,L,D] fp32
    float* attn_f = out_f + (size_t)M_ * D_;            // [N,H,L,L] fp32

    const int EW_GRID = (M_ * D_ / 4) / 256;            // 4096
    dim3 gemm_grid(M_ / 128, D_ / 128);                 // 32 x 8

    auto gemm = [&](const float* A, const float* B, const float* bias, float* C, int accum, int relu) {
        gemm_mfma_kernel<<<gemm_grid, 256, 0, stream>>>(A, B, bias, C, M_, D_, D_, accum, relu);
    };

    // pre-LN
    ln_kernel<<<M_, 256, 0, stream>>>(query, B0, ln1_s, ln1_b);
    ln_kernel<<<M_, 256, 0, stream>>>(value, B1, lnkv_s, lnkv_b);
    // per-head projections (k_ = v_)
    proj_kernel<<<M_, 256, 0, stream>>>(B0, B1, wq, wk, wv, B2, B3, B4);
    // fused energy + mask + softmax -> fp32 attn (output 1)
    attn_softmax_kernel<<<dim3(L_ / 8, H_, N_), 256, 0, stream>>>(B2, B3, mask, attn_f);
    // PV -> o (fp32, [N,L,H,hs] == [N,L,D])
    pv_kernel<<<dim3(L_ / 64, H_, N_), 256, 0, stream>>>(attn_f, B4, B0);
    // o_proj = o @ w_out.T + b_out
    gemm(B0, w_out, b_out, B1, 0, 0);

    // GRU gate 1: x = query, y = B1
    gemm(B1, g1_W, nullptr, B2, 0, 0);
    gemm(query, g1_U, nullptr, B2, 1, 0);
    gemm(B1, g1_W + DD_, nullptr, B3, 0, 0);
    gemm(query, g1_U + DD_, nullptr, B3, 1, 0);
    gemm(B1, g1_W + 2 * DD_, nullptr, B4, 0, 0);
    gate_rz_t_kernel<<<EW_GRID, 256, 0, stream>>>(B2, B3, query, g1_bg);
    gemm(B2, g1_U + 2 * DD_, nullptr, B4, 1, 0);
    gate_out_kernel<<<EW_GRID, 256, 0, stream>>>(B4, B3, query, B0);   // h -> B0

    // LN2 + FC
    ln_kernel<<<M_, 256, 0, stream>>>(B0, B2, ln2_s, ln2_b);
    gemm(B2, fc_w, fc_b, B1, 0, 1);                                    // f -> B1 (ReLU)

    // GRU gate 2: x = B0 (h), y = B1 (f)
    gemm(B1, g2_W, nullptr, B2, 0, 0);
    gemm(B0, g2_U, nullptr, B2, 1, 0);
    gemm(B1, g2_W + DD_, nullptr, B3, 0, 0);
    gemm(B0, g2_U + DD_, nullptr, B3, 1, 0);
    gemm(B1, g2_W + 2 * DD_, nullptr, B4, 0, 0);
    gate_rz_t_kernel<<<EW_GRID, 256, 0, stream>>>(B2, B3, B0, g2_bg);
    gemm(B2, g2_U + 2 * DD_, nullptr, B4, 1, 0);
    gate_out_kernel<<<EW_GRID, 256, 0, stream>>>(B4, B3, B0, out_f);   // out (fp32)
}

// Round 5
// 1027.305 us; speedup vs baseline: 2.2814x; 1.2054x over previous
//
#include <hip/hip_runtime.h>
#include <cstdint>
#include <cstddef>

#define N_ 4
#define L_ 1024
#define D_ 1024
#define H_ 16
#define HS_ 64
#define M_ (N_*L_)       // 4096 rows
#define DD_ (D_*D_)      // 1048576

typedef unsigned short u16;
typedef __bf16 b16x8 __attribute__((ext_vector_type(8)));
typedef float f32x4 __attribute__((ext_vector_type(4)));

__device__ __forceinline__ float sigmoidf_(float x) { return 1.0f / (1.0f + __expf(-x)); }
__device__ __forceinline__ u16 f2bf(float f) {
    union { float f; uint32_t u; } c; c.f = f;
    uint32_t u = c.u;
    u += 0x7fffu + ((u >> 16) & 1u);   // RNE
    return (u16)(u >> 16);
}

// ---------------- LayerNorm: one block per row of 1024 ----------------
__global__ __launch_bounds__(256) void ln_kernel(const float* __restrict__ x, float* __restrict__ y,
                                                 const float* __restrict__ sc, const float* __restrict__ bi) {
    int row = blockIdx.x;
    const float* xr = x + (size_t)row * D_;
    float* yr = y + (size_t)row * D_;
    int t = threadIdx.x;
    float4 v = *(const float4*)&xr[t * 4];
    float s = v.x + v.y + v.z + v.w;
    float q = v.x * v.x + v.y * v.y + v.z * v.z + v.w * v.w;
#pragma unroll
    for (int o = 32; o > 0; o >>= 1) { s += __shfl_xor(s, o); q += __shfl_xor(q, o); }
    __shared__ float ss[4], sq[4];
    int w = t >> 6;
    if ((t & 63) == 0) { ss[w] = s; sq[w] = q; }
    __syncthreads();
    s = ss[0] + ss[1] + ss[2] + ss[3];
    q = sq[0] + sq[1] + sq[2] + sq[3];
    float mean = s * (1.0f / D_);
    float var = q * (1.0f / D_) - mean * mean;
    float inv = rsqrtf(var + 1e-5f);
    float4 sv = *(const float4*)&sc[t * 4];
    float4 bv = *(const float4*)&bi[t * 4];
    float4 o4;
    o4.x = (v.x - mean) * inv * sv.x + bv.x;
    o4.y = (v.y - mean) * inv * sv.y + bv.y;
    o4.z = (v.z - mean) * inv * sv.z + bv.z;
    o4.w = (v.w - mean) * inv * sv.w + bv.w;
    *(float4*)&yr[t * 4] = o4;
}

// ------------- per-head projections: qh/kh -> bf16, vh -> fp32 -------------
__global__ __launch_bounds__(256) void proj_kernel(const float* __restrict__ qn, const float* __restrict__ vn,
                                                   const float* __restrict__ wq, const float* __restrict__ wk,
                                                   const float* __restrict__ wv,
                                                   u16* __restrict__ qh, u16* __restrict__ kh,
                                                   float* __restrict__ vh) {
    __shared__ float Wq[64 * 65], Wk[64 * 65], Wv[64 * 65];
    __shared__ float qrow[D_], vrow[D_];
    int t = threadIdx.x;
    size_t nl = blockIdx.x;
    for (int i = t; i < 4096; i += 256) {
        int d = i >> 6, k = i & 63;
        Wq[d * 65 + k] = wq[i];
        Wk[d * 65 + k] = wk[i];
        Wv[d * 65 + k] = wv[i];
    }
    *(float4*)&qrow[t * 4] = *(const float4*)&qn[nl * D_ + t * 4];
    *(float4*)&vrow[t * 4] = *(const float4*)&vn[nl * D_ + t * 4];
    __syncthreads();
#pragma unroll
    for (int rep = 0; rep < 4; ++rep) {
        int e = rep * 256 + t;
        int h = e >> 6, d = e & 63;
        const float* qr = &qrow[h * 64];
        const float* vr = &vrow[h * 64];
        float aq = 0.f, ak = 0.f, av = 0.f;
#pragma unroll 8
        for (int k = 0; k < 64; ++k) {
            float qv = qr[k], vv = vr[k];
            aq += qv * Wq[d * 65 + k];
            ak += vv * Wk[d * 65 + k];
            av += vv * Wv[d * 65 + k];
        }
        qh[nl * D_ + e] = f2bf(aq);
        kh[nl * D_ + e] = f2bf(ak);
        vh[nl * D_ + e] = av;
    }
}

// -------- transpose V per head: vh[n,k,h,d] fp32 -> vt[n,h,d,k] bf16 --------
__global__ __launch_bounds__(256) void vtrans_kernel(const float* __restrict__ vh, u16* __restrict__ vt) {
    __shared__ float tile[64 * 65];
    int t = threadIdx.x;
    int kc = blockIdx.x * 64, h = blockIdx.y, n = blockIdx.z;
    {
        int k = t >> 2, dc = (t & 3) * 16;
        const float* src = &vh[((size_t)(n * L_ + kc + k) * H_ + h) * HS_ + dc];
#pragma unroll
        for (int i = 0; i < 4; ++i)
            *(float4*)&tile[k * 65 + dc + i * 4] = *(const float4*)&src[i * 4];
    }
    __syncthreads();
    {
        int d = t >> 2, kk = (t & 3) * 16;
        u16 outv[16];
#pragma unroll
        for (int i = 0; i < 16; ++i) outv[i] = f2bf(tile[(kk + i) * 65 + d]);
        u16* dst = &vt[((size_t)(n * H_ + h) * HS_ + d) * L_ + kc + kk];
        *(uint4*)&dst[0] = *(uint4*)&outv[0];
        *(uint4*)&dst[8] = *(uint4*)&outv[8];
    }
}

// -------- MFMA QK^T + softmax: block = 32 q rows x full L, 8 waves --------
// wave w: qsub = w&1 (16 q), kq = w>>1 (256 k). Scores in registers, no LDS in hot loop.
__global__ __launch_bounds__(512, 2) void qk_softmax_kernel(const u16* __restrict__ qh,
                                                            const u16* __restrict__ kh,
                                                            const int* __restrict__ mask,
                                                            float* __restrict__ attn) {
    int t = threadIdx.x;
    int w = t >> 6, l = t & 63;
    int qsub = w & 1, kq = w >> 1;
    int q0 = blockIdx.x * 32;
    int h = blockIdx.y, n = blockIdx.z;
    int lr = l & 15, lg = l >> 4;

    // Q fragments (A-side): row q0+qsub*16+lr, d = lg*8 (+32)
    size_t qrow = ((size_t)(n * L_ + q0 + qsub * 16 + lr) * H_ + h) * HS_;
    b16x8 aq0 = *(const b16x8*)&qh[qrow + lg * 8];
    b16x8 aq1 = *(const b16x8*)&qh[qrow + 32 + lg * 8];

    f32x4 c[16];
#pragma unroll
    for (int i = 0; i < 16; ++i) c[i] = (f32x4){0.f, 0.f, 0.f, 0.f};

    // K fragments (B-side) streamed from global; row stride per k-tile = 16*D_
    size_t kbase = ((size_t)(n * L_ + kq * 256 + lr) * H_ + h) * HS_ + lg * 8;
#pragma unroll
    for (int kt = 0; kt < 16; ++kt) {
        const u16* kp = &kh[kbase + (size_t)kt * 16 * D_];
        b16x8 bk0 = *(const b16x8*)&kp[0];
        b16x8 bk1 = *(const b16x8*)&kp[32];
        c[kt] = __builtin_amdgcn_mfma_f32_16x16x32_bf16(aq0, bk0, c[kt], 0, 0, 0);
        c[kt] = __builtin_amdgcn_mfma_f32_16x16x32_bf16(aq1, bk1, c[kt], 0, 0, 0);
    }

    // mask + scale; C layout: row q = qsub*16 + lg*4 + r, col k = kq*256 + kt*16 + lr
    const float scl = 0.03125f;   // 1/sqrt(1024)
    int kcol = kq * 256 + lr;
    float rowmax[4] = { -1e30f, -1e30f, -1e30f, -1e30f };
#pragma unroll
    for (int kt = 0; kt < 16; ++kt) {
        int mk = mask[n * L_ + kcol + kt * 16];
#pragma unroll
        for (int r = 0; r < 4; ++r) {
            float s = (mk != 0) ? c[kt][r] * scl : -1e20f;
            c[kt][r] = s;
            rowmax[r] = fmaxf(rowmax[r], s);
        }
    }
#pragma unroll
    for (int o = 8; o > 0; o >>= 1)
#pragma unroll
        for (int r = 0; r < 4; ++r) rowmax[r] = fmaxf(rowmax[r], __shfl_xor(rowmax[r], o));

    __shared__ float redA[32][4];
    __shared__ float redB[32][4];
    int qrow4 = qsub * 16 + lg * 4;
    if (lr == 0) {
#pragma unroll
        for (int r = 0; r < 4; ++r) redA[qrow4 + r][kq] = rowmax[r];
    }
    __syncthreads();
#pragma unroll
    for (int r = 0; r < 4; ++r) {
        float m = fmaxf(fmaxf(redA[qrow4 + r][0], redA[qrow4 + r][1]),
                        fmaxf(redA[qrow4 + r][2], redA[qrow4 + r][3]));
        rowmax[r] = m;
    }
    float rowsum[4] = { 0.f, 0.f, 0.f, 0.f };
#pragma unroll
    for (int kt = 0; kt < 16; ++kt)
#pragma unroll
        for (int r = 0; r < 4; ++r) {
            float e = __expf(c[kt][r] - rowmax[r]);
            c[kt][r] = e;
            rowsum[r] += e;
        }
#pragma unroll
    for (int o = 8; o > 0; o >>= 1)
#pragma unroll
        for (int r = 0; r < 4; ++r) rowsum[r] += __shfl_xor(rowsum[r], o);
    if (lr == 0) {
#pragma unroll
        for (int r = 0; r < 4; ++r) redB[qrow4 + r][kq] = rowsum[r];
    }
    __syncthreads();
    float inv[4];
#pragma unroll
    for (int r = 0; r < 4; ++r)
        inv[r] = 1.0f / (redB[qrow4 + r][0] + redB[qrow4 + r][1] +
                         redB[qrow4 + r][2] + redB[qrow4 + r][3]);

    float* ap = attn + ((size_t)((n * H_ + h) * L_) + q0 + qrow4) * L_ + kcol;
#pragma unroll
    for (int kt = 0; kt < 16; ++kt)
#pragma unroll
        for (int r = 0; r < 4; ++r)
            ap[(size_t)r * L_ + kt * 16] = c[kt][r] * inv[r];
}

// -------- MFMA PV: O^T[d][q] = sum_k V^T[d][k] * P[q][k] per (n,h) --------
// block: 128 q x 64 d, 4 waves (wave w: q in [w*32, w*32+32)), K-step 32.
#define PLD 40
__global__ __launch_bounds__(256) void pv_mfma_kernel(const float* __restrict__ attn,
                                                      const u16* __restrict__ vt,
                                                      float* __restrict__ o) {
    __shared__ u16 a_lds[128 * PLD];
    __shared__ u16 v_lds[64 * PLD];
    int t = threadIdx.x, w = t >> 6, l = t & 63;
    int lr = l & 15, lg = l >> 4;
    int qb = blockIdx.x * 128, h = blockIdx.y, n = blockIdx.z;
    const float* abase = attn + ((size_t)((n * H_ + h) * L_) + qb) * L_;
    const u16* vbase = vt + (size_t)(n * H_ + h) * HS_ * L_;
    f32x4 acc[4][2];
#pragma unroll
    for (int i = 0; i < 4; ++i)
#pragma unroll
        for (int j = 0; j < 2; ++j) acc[i][j] = (f32x4){0.f, 0.f, 0.f, 0.f};

    int sq = t >> 1, sk = (t & 1) * 16;       // attn staging: row, 16-k chunk
    int vd = t >> 2, vk = (t & 3) * 8;        // vt staging
    for (int kb = 0; kb < L_; kb += 32) {
        float va[16];
#pragma unroll
        for (int i = 0; i < 4; ++i)
            *(float4*)&va[i * 4] = *(const float4*)&abase[(size_t)sq * L_ + kb + sk + i * 4];
        b16x8 vv = *(const b16x8*)&vbase[(size_t)vd * L_ + kb + vk];
        u16 ua[16];
#pragma unroll
        for (int i = 0; i < 16; ++i) ua[i] = f2bf(va[i]);
        __syncthreads();
        *(uint4*)&a_lds[sq * PLD + sk] = *(uint4*)&ua[0];
        *(uint4*)&a_lds[sq * PLD + sk + 8] = *(uint4*)&ua[8];
        *(b16x8*)&v_lds[vd * PLD + vk] = vv;
        __syncthreads();
        b16x8 bq[2];
#pragma unroll
        for (int qt = 0; qt < 2; ++qt)
            bq[qt] = *(const b16x8*)&a_lds[(w * 32 + qt * 16 + lr) * PLD + lg * 8];
#pragma unroll
        for (int dt = 0; dt < 4; ++dt) {
            b16x8 av = *(const b16x8*)&v_lds[(dt * 16 + lr) * PLD + lg * 8];
#pragma unroll
            for (int qt = 0; qt < 2; ++qt)
                acc[dt][qt] = __builtin_amdgcn_mfma_f32_16x16x32_bf16(av, bq[qt], acc[dt][qt], 0, 0, 0);
        }
    }
#pragma unroll
    for (int dt = 0; dt < 4; ++dt)
#pragma unroll
        for (int qt = 0; qt < 2; ++qt) {
            int q = qb + w * 32 + qt * 16 + lr;
            int d = dt * 16 + lg * 4;
            float4 val = { acc[dt][qt][0], acc[dt][qt][1], acc[dt][qt][2], acc[dt][qt][3] };
            *(float4*)&o[((size_t)(n * L_ + q) * H_ + h) * HS_ + d] = val;
        }
}

// ---------- MFMA GEMM: C[M,N] (+)= A[M,K] @ B[N,K]^T (+bias)(ReLU), fp32 io, bf16 compute ----------
#define LDQ 40
__global__ __launch_bounds__(256) void gemm_mfma_kernel(const float* __restrict__ A,
                                                        const float* __restrict__ B,
                                                        const float* __restrict__ bias,
                                                        float* __restrict__ C,
                                                        int M, int N, int K, int accum, int relu) {
    __shared__ unsigned short As[128 * LDQ];
    __shared__ unsigned short Bs[128 * LDQ];
    int t = threadIdx.x;
    int l = t & 63, w = t >> 6;
    int wr = w >> 1, wc = w & 1;
    int m0 = blockIdx.x * 128, n0 = blockIdx.y * 128;
    int sr = t >> 1, sc = (t & 1) * 16;
    const float* Ag = A + (size_t)(m0 + sr) * K + sc;
    const float* Bg = B + (size_t)(n0 + sr) * K + sc;
    int fr = l & 15, fq = l >> 4;

    f32x4 acc[4][4];
#pragma unroll
    for (int i = 0; i < 4; ++i)
#pragma unroll
        for (int j = 0; j < 4; ++j) acc[i][j] = (f32x4){0.f, 0.f, 0.f, 0.f};

    float ra[16], rb[16];
#pragma unroll
    for (int i = 0; i < 4; ++i) {
        *(float4*)&ra[i * 4] = *(const float4*)&Ag[i * 4];
        *(float4*)&rb[i * 4] = *(const float4*)&Bg[i * 4];
    }
    for (int kk = 0; kk < K; kk += 32) {
        __syncthreads();
        unsigned short ta[16], tb[16];
#pragma unroll
        for (int i = 0; i < 16; ++i) { ta[i] = f2bf(ra[i]); tb[i] = f2bf(rb[i]); }
#pragma unroll
        for (int i = 0; i < 4; ++i) {
            *(ushort4*)&As[sr * LDQ + sc + i * 4] = *(ushort4*)&ta[i * 4];
            *(ushort4*)&Bs[sr * LDQ + sc + i * 4] = *(ushort4*)&tb[i * 4];
        }
        if (kk + 32 < K) {
#pragma unroll
            for (int i = 0; i < 4; ++i) {
                *(float4*)&ra[i * 4] = *(const float4*)&Ag[kk + 32 + i * 4];
                *(float4*)&rb[i * 4] = *(const float4*)&Bg[kk + 32 + i * 4];
            }
        }
        __syncthreads();
        b16x8 af[4], bfr[4];
#pragma unroll
        for (int i = 0; i < 4; ++i) {
            af[i]  = *(const b16x8*)&As[(wr * 64 + i * 16 + fr) * LDQ + fq * 8];
            bfr[i] = *(const b16x8*)&Bs[(wc * 64 + i * 16 + fr) * LDQ + fq * 8];
        }
#pragma unroll
        for (int i = 0; i < 4; ++i)
#pragma unroll
            for (int j = 0; j < 4; ++j)
                acc[i][j] = __builtin_amdgcn_mfma_f32_16x16x32_bf16(af[i], bfr[j], acc[i][j], 0, 0, 0);
    }
#pragma unroll
    for (int i = 0; i < 4; ++i) {
#pragma unroll
        for (int j = 0; j < 4; ++j) {
            int row = m0 + wr * 64 + i * 16 + fq * 4;
            int col = n0 + wc * 64 + j * 16 + fr;
            float bv = bias ? bias[col] : 0.f;
#pragma unroll
            for (int r = 0; r < 4; ++r) {
                size_t off = (size_t)(row + r) * N + col;
                float v = acc[i][j][r] + bv;
                if (accum) v += C[off];
                if (relu) v = fmaxf(v, 0.f);
                C[off] = v;
            }
        }
    }
}

// ---------- GRU gate elementwise ----------
__global__ __launch_bounds__(256) void gate_rz_t_kernel(float* __restrict__ rp, float* __restrict__ zp,
                                                        const float* __restrict__ x, const float* __restrict__ bg) {
    int i = blockIdx.x * 256 + threadIdx.x;
    float4 r4 = ((const float4*)rp)[i];
    float4 z4 = ((const float4*)zp)[i];
    float4 x4 = ((const float4*)x)[i];
    float4 b4 = *(const float4*)&bg[(i & 255) * 4];
    float4 t4, zz;
    t4.x = sigmoidf_(r4.x) * x4.x; zz.x = sigmoidf_(z4.x - b4.x);
    t4.y = sigmoidf_(r4.y) * x4.y; zz.y = sigmoidf_(z4.y - b4.y);
    t4.z = sigmoidf_(r4.z) * x4.z; zz.z = sigmoidf_(z4.z - b4.z);
    t4.w = sigmoidf_(r4.w) * x4.w; zz.w = sigmoidf_(z4.w - b4.w);
    ((float4*)rp)[i] = t4;
    ((float4*)zp)[i] = zz;
}

__global__ __launch_bounds__(256) void gate_out_kernel(const float* __restrict__ hp, const float* __restrict__ z,
                                                       const float* __restrict__ x, float* __restrict__ outf) {
    int i = blockIdx.x * 256 + threadIdx.x;
    float4 h4 = ((const float4*)hp)[i];
    float4 z4 = ((const float4*)z)[i];
    float4 x4 = ((const float4*)x)[i];
    float4 o;
    o.x = (1.f - z4.x) * x4.x + z4.x * tanhf(h4.x);
    o.y = (1.f - z4.y) * x4.y + z4.y * tanhf(h4.y);
    o.z = (1.f - z4.z) * x4.z + z4.z * tanhf(h4.z);
    o.w = (1.f - z4.w) * x4.w + z4.w * tanhf(h4.w);
    ((float4*)outf)[i] = o;
}

extern "C" void kernel_launch(void* const* d_in, const int* in_sizes, int n_in,
                              void* d_out, int out_size, void* d_ws, size_t ws_size,
                              hipStream_t stream) {
    const float* value = (const float*)d_in[0];
    // d_in[1] = key (unused: reference sets k_ = normed value)
    const float* query = (const float*)d_in[2];
    const int* mask = (const int*)d_in[3];
    const float* wq = (const float*)d_in[4];
    const float* wk = (const float*)d_in[5];
    const float* wv = (const float*)d_in[6];
    const float* w_out = (const float*)d_in[7];
    const float* b_out = (const float*)d_in[8];
    const float* fc_w = (const float*)d_in[9];
    const float* fc_b = (const float*)d_in[10];
    const float* ln1_s = (const float*)d_in[11];
    const float* ln1_b = (const float*)d_in[12];
    const float* lnkv_s = (const float*)d_in[13];
    const float* lnkv_b = (const float*)d_in[14];
    const float* ln2_s = (const float*)d_in[15];
    const float* ln2_b = (const float*)d_in[16];
    const float* g1_W = (const float*)d_in[17];
    const float* g1_U = (const float*)d_in[18];
    const float* g1_bg = (const float*)d_in[19];
    const float* g2_W = (const float*)d_in[20];
    const float* g2_U = (const float*)d_in[21];
    const float* g2_bg = (const float*)d_in[22];

    float* B0 = (float*)d_ws;
    float* B1 = B0 + (size_t)M_ * D_;
    float* B2 = B1 + (size_t)M_ * D_;
    float* B3 = B2 + (size_t)M_ * D_;
    float* B4 = B3 + (size_t)M_ * D_;

    // attention-phase aliases (within B2..B4, freed before the GEMM chain reuses them)
    u16* qh_bf = (u16*)B2;                       // 8MB
    u16* kh_bf = qh_bf + (size_t)M_ * D_;        // 8MB (second half of B2)
    float* vh_f = B3;                            // 16MB
    u16* vh_t = (u16*)B4;                        // 8MB

    float* out_f = (float*)d_out;                // [N,L,D] fp32
    float* attn_f = out_f + (size_t)M_ * D_;     // [N,H,L,L] fp32

    const int EW_GRID = (M_ * D_ / 4) / 256;     // 4096
    dim3 gemm_grid(M_ / 128, D_ / 128);          // 32 x 8

    auto gemm = [&](const float* A, const float* B, const float* bias, float* C, int accum, int relu) {
        gemm_mfma_kernel<<<gemm_grid, 256, 0, stream>>>(A, B, bias, C, M_, D_, D_, accum, relu);
    };

    // pre-LN
    ln_kernel<<<M_, 256, 0, stream>>>(query, B0, ln1_s, ln1_b);
    ln_kernel<<<M_, 256, 0, stream>>>(value, B1, lnkv_s, lnkv_b);
    // per-head projections (k_ = v_): qh/kh bf16, vh fp32
    proj_kernel<<<M_, 256, 0, stream>>>(B0, B1, wq, wk, wv, qh_bf, kh_bf, vh_f);
    // V transpose -> [n,h,d,k] bf16
    vtrans_kernel<<<dim3(L_ / 64, H_, N_), 256, 0, stream>>>(vh_f, vh_t);
    // MFMA QK^T + softmax -> fp32 attn (output 1)
    qk_softmax_kernel<<<dim3(L_ / 32, H_, N_), 512, 0, stream>>>(qh_bf, kh_bf, mask, attn_f);
    // MFMA PV -> o (fp32, [N,L,H,hs] == [N,L,D])
    pv_mfma_kernel<<<dim3(L_ / 128, H_, N_), 256, 0, stream>>>(attn_f, vh_t, B0);
    // o_proj = o @ w_out.T + b_out
    gemm(B0, w_out, b_out, B1, 0, 0);

    // GRU gate 1: x = query, y = B1
    gemm(B1, g1_W, nullptr, B2, 0, 0);
    gemm(query, g1_U, nullptr, B2, 1, 0);
    gemm(B1, g1_W + DD_, nullptr, B3, 0, 0);
    gemm(query, g1_U + DD_, nullptr, B3, 1, 0);
    gemm(B1, g1_W + 2 * DD_, nullptr, B4, 0, 0);
    gate_rz_t_kernel<<<EW_GRID, 256, 0, stream>>>(B2, B3, query, g1_bg);
    gemm(B2, g1_U + 2 * DD_, nullptr, B4, 1, 0);
    gate_out_kernel<<<EW_GRID, 256, 0, stream>>>(B4, B3, query, B0);   // h -> B0

    // LN2 + FC
    ln_kernel<<<M_, 256, 0, stream>>>(B0, B2, ln2_s, ln2_b);
    gemm(B2, fc_w, fc_b, B1, 0, 1);                                    // f -> B1 (ReLU)

    // GRU gate 2: x = B0 (h), y = B1 (f)
    gemm(B1, g2_W, nullptr, B2, 0, 0);
    gemm(B0, g2_U, nullptr, B2, 1, 0);
    gemm(B1, g2_W + DD_, nullptr, B3, 0, 0);
    gemm(B0, g2_U + DD_, nullptr, B3, 1, 0);
    gemm(B1, g2_W + 2 * DD_, nullptr, B4, 0, 0);
    gate_rz_t_kernel<<<EW_GRID, 256, 0, stream>>>(B2, B3, B0, g2_bg);
    gemm(B2, g2_U + 2 * DD_, nullptr, B4, 1, 0);
    gate_out_kernel<<<EW_GRID, 256, 0, stream>>>(B4, B3, B0, out_f);   // out (fp32)
}

// Round 6
// 672.367 us; speedup vs baseline: 3.4857x; 1.5279x over previous
//
#include <hip/hip_runtime.h>
#include <cstdint>
#include <cstddef>

#define N_ 4
#define L_ 1024
#define D_ 1024
#define H_ 16
#define HS_ 64
#define M_ (N_*L_)       // 4096 rows
#define DD_ (D_*D_)      // 1048576

typedef unsigned short u16;
typedef __bf16 b16x8 __attribute__((ext_vector_type(8)));
typedef float f32x4 __attribute__((ext_vector_type(4)));

__device__ __forceinline__ float sigmoidf_(float x) { return 1.0f / (1.0f + __expf(-x)); }
__device__ __forceinline__ u16 f2bf(float f) {
    union { float f; uint32_t u; } c; c.f = f;
    uint32_t u = c.u;
    u += 0x7fffu + ((u >> 16) & 1u);   // RNE
    return (u16)(u >> 16);
}

// async global->LDS, 16B per lane; LDS dest = wave-uniform base + lane*16 (CK cast pattern)
__device__ __forceinline__ void gl_lds16(const void* g, void* l) {
    auto gp = reinterpret_cast<const __attribute__((address_space(1))) unsigned int*>(
        reinterpret_cast<uintptr_t>(g));
    auto lp = reinterpret_cast<__attribute__((address_space(3))) unsigned int*>(
        reinterpret_cast<uintptr_t>(l));
    __builtin_amdgcn_global_load_lds(gp, lp, 16, 0, 0);
}

// ---------------- fp32 -> bf16 elementwise (n = gridDim*2048 elems) ----------------
__global__ __launch_bounds__(256) void cvt_kernel(const float* __restrict__ src, u16* __restrict__ dst) {
    size_t i = ((size_t)blockIdx.x * 256 + threadIdx.x) * 8;
    float4 a = *(const float4*)&src[i];
    float4 b = *(const float4*)&src[i + 4];
    u16 o[8] = { f2bf(a.x), f2bf(a.y), f2bf(a.z), f2bf(a.w),
                 f2bf(b.x), f2bf(b.y), f2bf(b.z), f2bf(b.w) };
    *(uint4*)&dst[i] = *(uint4*)o;
}

// ---------------- LayerNorm: one block per row; OBF: emit bf16 ----------------
template<int OBF>
__global__ __launch_bounds__(256) void ln_kernel(const float* __restrict__ x, void* __restrict__ y,
                                                 const float* __restrict__ sc, const float* __restrict__ bi) {
    int row = blockIdx.x;
    const float* xr = x + (size_t)row * D_;
    int t = threadIdx.x;
    float4 v = *(const float4*)&xr[t * 4];
    float s = v.x + v.y + v.z + v.w;
    float q = v.x * v.x + v.y * v.y + v.z * v.z + v.w * v.w;
#pragma unroll
    for (int o = 32; o > 0; o >>= 1) { s += __shfl_xor(s, o); q += __shfl_xor(q, o); }
    __shared__ float ss[4], sq[4];
    int w = t >> 6;
    if ((t & 63) == 0) { ss[w] = s; sq[w] = q; }
    __syncthreads();
    s = ss[0] + ss[1] + ss[2] + ss[3];
    q = sq[0] + sq[1] + sq[2] + sq[3];
    float mean = s * (1.0f / D_);
    float var = q * (1.0f / D_) - mean * mean;
    float inv = rsqrtf(var + 1e-5f);
    float4 sv = *(const float4*)&sc[t * 4];
    float4 bv = *(const float4*)&bi[t * 4];
    float4 o4;
    o4.x = (v.x - mean) * inv * sv.x + bv.x;
    o4.y = (v.y - mean) * inv * sv.y + bv.y;
    o4.z = (v.z - mean) * inv * sv.z + bv.z;
    o4.w = (v.w - mean) * inv * sv.w + bv.w;
    if (OBF) {
        u16 ov[4] = { f2bf(o4.x), f2bf(o4.y), f2bf(o4.z), f2bf(o4.w) };
        *(ushort4*)&((u16*)y)[(size_t)row * D_ + t * 4] = *(ushort4*)ov;
    } else {
        *(float4*)&((float*)y)[(size_t)row * D_ + t * 4] = o4;
    }
}

// ------------- per-head projections: qh/kh -> bf16, vh -> fp32 -------------
__global__ __launch_bounds__(256) void proj_kernel(const float* __restrict__ qn, const float* __restrict__ vn,
                                                   const float* __restrict__ wq, const float* __restrict__ wk,
                                                   const float* __restrict__ wv,
                                                   u16* __restrict__ qh, u16* __restrict__ kh,
                                                   float* __restrict__ vh) {
    __shared__ float Wq[64 * 65], Wk[64 * 65], Wv[64 * 65];
    __shared__ float qrow[D_], vrow[D_];
    int t = threadIdx.x;
    size_t nl = blockIdx.x;
    for (int i = t; i < 4096; i += 256) {
        int d = i >> 6, k = i & 63;
        Wq[d * 65 + k] = wq[i];
        Wk[d * 65 + k] = wk[i];
        Wv[d * 65 + k] = wv[i];
    }
    *(float4*)&qrow[t * 4] = *(const float4*)&qn[nl * D_ + t * 4];
    *(float4*)&vrow[t * 4] = *(const float4*)&vn[nl * D_ + t * 4];
    __syncthreads();
#pragma unroll
    for (int rep = 0; rep < 4; ++rep) {
        int e = rep * 256 + t;
        int h = e >> 6, d = e & 63;
        const float* qr = &qrow[h * 64];
        const float* vr = &vrow[h * 64];
        float aq = 0.f, ak = 0.f, av = 0.f;
#pragma unroll 8
        for (int k = 0; k < 64; ++k) {
            float qv = qr[k], vv = vr[k];
            aq += qv * Wq[d * 65 + k];
            ak += vv * Wk[d * 65 + k];
            av += vv * Wv[d * 65 + k];
        }
        qh[nl * D_ + e] = f2bf(aq);
        kh[nl * D_ + e] = f2bf(ak);
        vh[nl * D_ + e] = av;
    }
}

// -------- transpose V per head: vh[n,k,h,d] fp32 -> vt[n,h,d,k] bf16 --------
__global__ __launch_bounds__(256) void vtrans_kernel(const float* __restrict__ vh, u16* __restrict__ vt) {
    __shared__ float tile[64 * 65];
    int t = threadIdx.x;
    int kc = blockIdx.x * 64, h = blockIdx.y, n = blockIdx.z;
    {
        int k = t >> 2, dc = (t & 3) * 16;
        const float* src = &vh[((size_t)(n * L_ + kc + k) * H_ + h) * HS_ + dc];
#pragma unroll
        for (int i = 0; i < 4; ++i)
            *(float4*)&tile[k * 65 + dc + i * 4] = *(const float4*)&src[i * 4];
    }
    __syncthreads();
    {
        int d = t >> 2, kk = (t & 3) * 16;
        u16 outv[16];
#pragma unroll
        for (int i = 0; i < 16; ++i) outv[i] = f2bf(tile[(kk + i) * 65 + d]);
        u16* dst = &vt[((size_t)(n * H_ + h) * HS_ + d) * L_ + kc + kk];
        *(uint4*)&dst[0] = *(uint4*)&outv[0];
        *(uint4*)&dst[8] = *(uint4*)&outv[8];
    }
}

// -------- MFMA QK^T + softmax: block = 32 q rows x full L, 8 waves --------
__global__ __launch_bounds__(512, 2) void qk_softmax_kernel(const u16* __restrict__ qh,
                                                            const u16* __restrict__ kh,
                                                            const int* __restrict__ mask,
                                                            float* __restrict__ attn) {
    int t = threadIdx.x;
    int w = t >> 6, l = t & 63;
    int qsub = w & 1, kq = w >> 1;
    int q0 = blockIdx.x * 32;
    int h = blockIdx.y, n = blockIdx.z;
    int lr = l & 15, lg = l >> 4;

    size_t qrow = ((size_t)(n * L_ + q0 + qsub * 16 + lr) * H_ + h) * HS_;
    b16x8 aq0 = *(const b16x8*)&qh[qrow + lg * 8];
    b16x8 aq1 = *(const b16x8*)&qh[qrow + 32 + lg * 8];

    f32x4 c[16];
#pragma unroll
    for (int i = 0; i < 16; ++i) c[i] = (f32x4){0.f, 0.f, 0.f, 0.f};

    size_t kbase = ((size_t)(n * L_ + kq * 256 + lr) * H_ + h) * HS_ + lg * 8;
#pragma unroll
    for (int kt = 0; kt < 16; ++kt) {
        const u16* kp = &kh[kbase + (size_t)kt * 16 * D_];
        b16x8 bk0 = *(const b16x8*)&kp[0];
        b16x8 bk1 = *(const b16x8*)&kp[32];
        c[kt] = __builtin_amdgcn_mfma_f32_16x16x32_bf16(aq0, bk0, c[kt], 0, 0, 0);
        c[kt] = __builtin_amdgcn_mfma_f32_16x16x32_bf16(aq1, bk1, c[kt], 0, 0, 0);
    }

    const float scl = 0.03125f;   // 1/sqrt(1024)
    int kcol = kq * 256 + lr;
    float rowmax[4] = { -1e30f, -1e30f, -1e30f, -1e30f };
#pragma unroll
    for (int kt = 0; kt < 16; ++kt) {
        int mk = mask[n * L_ + kcol + kt * 16];
#pragma unroll
        for (int r = 0; r < 4; ++r) {
            float s = (mk != 0) ? c[kt][r] * scl : -1e20f;
            c[kt][r] = s;
            rowmax[r] = fmaxf(rowmax[r], s);
        }
    }
#pragma unroll
    for (int o = 8; o > 0; o >>= 1)
#pragma unroll
        for (int r = 0; r < 4; ++r) rowmax[r] = fmaxf(rowmax[r], __shfl_xor(rowmax[r], o));

    __shared__ float redA[32][4];
    __shared__ float redB[32][4];
    int qrow4 = qsub * 16 + lg * 4;
    if (lr == 0) {
#pragma unroll
        for (int r = 0; r < 4; ++r) redA[qrow4 + r][kq] = rowmax[r];
    }
    __syncthreads();
#pragma unroll
    for (int r = 0; r < 4; ++r)
        rowmax[r] = fmaxf(fmaxf(redA[qrow4 + r][0], redA[qrow4 + r][1]),
                          fmaxf(redA[qrow4 + r][2], redA[qrow4 + r][3]));
    float rowsum[4] = { 0.f, 0.f, 0.f, 0.f };
#pragma unroll
    for (int kt = 0; kt < 16; ++kt)
#pragma unroll
        for (int r = 0; r < 4; ++r) {
            float e = __expf(c[kt][r] - rowmax[r]);
            c[kt][r] = e;
            rowsum[r] += e;
        }
#pragma unroll
    for (int o = 8; o > 0; o >>= 1)
#pragma unroll
        for (int r = 0; r < 4; ++r) rowsum[r] += __shfl_xor(rowsum[r], o);
    if (lr == 0) {
#pragma unroll
        for (int r = 0; r < 4; ++r) redB[qrow4 + r][kq] = rowsum[r];
    }
    __syncthreads();
    float inv[4];
#pragma unroll
    for (int r = 0; r < 4; ++r)
        inv[r] = 1.0f / (redB[qrow4 + r][0] + redB[qrow4 + r][1] +
                         redB[qrow4 + r][2] + redB[qrow4 + r][3]);

    float* ap = attn + ((size_t)((n * H_ + h) * L_) + q0 + qrow4) * L_ + kcol;
#pragma unroll
    for (int kt = 0; kt < 16; ++kt)
#pragma unroll
        for (int r = 0; r < 4; ++r)
            ap[(size_t)r * L_ + kt * 16] = c[kt][r] * inv[r];
}

// -------- MFMA PV: O^T[d][q] per (n,h); output bf16 [n,q,h,d] --------
#define PLD 40
__global__ __launch_bounds__(256) void pv_mfma_kernel(const float* __restrict__ attn,
                                                      const u16* __restrict__ vt,
                                                      u16* __restrict__ o) {
    __shared__ u16 a_lds[128 * PLD];
    __shared__ u16 v_lds[64 * PLD];
    int t = threadIdx.x, w = t >> 6, l = t & 63;
    int lr = l & 15, lg = l >> 4;
    int qb = blockIdx.x * 128, h = blockIdx.y, n = blockIdx.z;
    const float* abase = attn + ((size_t)((n * H_ + h) * L_) + qb) * L_;
    const u16* vbase = vt + (size_t)(n * H_ + h) * HS_ * L_;
    f32x4 acc[4][2];
#pragma unroll
    for (int i = 0; i < 4; ++i)
#pragma unroll
        for (int j = 0; j < 2; ++j) acc[i][j] = (f32x4){0.f, 0.f, 0.f, 0.f};

    int sq = t >> 1, sk = (t & 1) * 16;
    int vd = t >> 2, vk = (t & 3) * 8;
    for (int kb = 0; kb < L_; kb += 32) {
        float va[16];
#pragma unroll
        for (int i = 0; i < 4; ++i)
            *(float4*)&va[i * 4] = *(const float4*)&abase[(size_t)sq * L_ + kb + sk + i * 4];
        b16x8 vv = *(const b16x8*)&vbase[(size_t)vd * L_ + kb + vk];
        u16 ua[16];
#pragma unroll
        for (int i = 0; i < 16; ++i) ua[i] = f2bf(va[i]);
        __syncthreads();
        *(uint4*)&a_lds[sq * PLD + sk] = *(uint4*)&ua[0];
        *(uint4*)&a_lds[sq * PLD + sk + 8] = *(uint4*)&ua[8];
        *(b16x8*)&v_lds[vd * PLD + vk] = vv;
        __syncthreads();
        b16x8 bq[2];
#pragma unroll
        for (int qt = 0; qt < 2; ++qt)
            bq[qt] = *(const b16x8*)&a_lds[(w * 32 + qt * 16 + lr) * PLD + lg * 8];
#pragma unroll
        for (int dt = 0; dt < 4; ++dt) {
            b16x8 av = *(const b16x8*)&v_lds[(dt * 16 + lr) * PLD + lg * 8];
#pragma unroll
            for (int qt = 0; qt < 2; ++qt)
                acc[dt][qt] = __builtin_amdgcn_mfma_f32_16x16x32_bf16(av, bq[qt], acc[dt][qt], 0, 0, 0);
        }
    }
#pragma unroll
    for (int dt = 0; dt < 4; ++dt)
#pragma unroll
        for (int qt = 0; qt < 2; ++qt) {
            int q = qb + w * 32 + qt * 16 + lr;
            int d = dt * 16 + lg * 4;
            u16 ov[4] = { f2bf(acc[dt][qt][0]), f2bf(acc[dt][qt][1]),
                          f2bf(acc[dt][qt][2]), f2bf(acc[dt][qt][3]) };
            *(ushort4*)&o[((size_t)(n * L_ + q) * H_ + h) * HS_ + d] = *(ushort4*)ov;
        }
}

// ---------- bf16 GEMM: C[M,N] (+)= A[M,K] @ B[N,K]^T (+bias)(ReLU) ----------
// 128x128 tile, 4 waves, BK=64, dbuf global_load_lds w16, counted vmcnt, XOR-swizzled LDS.
template<int ACCUM, int RELU, int OBF>
__global__ __launch_bounds__(256) void gemm_bf16_kernel(const u16* __restrict__ A,
                                                        const u16* __restrict__ Bw,
                                                        const float* __restrict__ bias,
                                                        float* __restrict__ C,
                                                        u16* __restrict__ Cbf,
                                                        int M, int N, int K) {
    __shared__ u16 As[2][128 * 64];
    __shared__ u16 Bs[2][128 * 64];
    int t = threadIdx.x, w = t >> 6, l = t & 63;
    int wr = w >> 1, wc = w & 1;
    int m0 = blockIdx.x * 128, n0 = blockIdx.y * 128;
    int fr = l & 15, fq = l >> 4;
    int srow = l >> 3;
    int gc8 = (l & 7) ^ (srow & 7);          // pre-swizzled source col-group (involution)
    const u16* Abase = A + (size_t)m0 * K;
    const u16* Bbase = Bw + (size_t)n0 * K;

    f32x4 acc[4][4];
#pragma unroll
    for (int i = 0; i < 4; ++i)
#pragma unroll
        for (int j = 0; j < 4; ++j) acc[i][j] = (f32x4){0.f, 0.f, 0.f, 0.f};

    auto STAGE = [&](int buf, int kk) {
#pragma unroll
        for (int i = 0; i < 4; ++i) {
            int r0 = (i * 4 + w) * 8;
            gl_lds16(&Abase[(size_t)(r0 + srow) * K + kk + gc8 * 8], &As[buf][r0 * 64]);
            gl_lds16(&Bbase[(size_t)(r0 + srow) * K + kk + gc8 * 8], &Bs[buf][r0 * 64]);
        }
    };
    STAGE(0, 0);
    const int NT = K >> 6;
    for (int kt = 0; kt < NT; ++kt) {
        int cur = kt & 1;
        if (kt + 1 < NT) {
            STAGE(cur ^ 1, (kt + 1) << 6);
            asm volatile("s_waitcnt vmcnt(8)" ::: "memory");
        } else {
            asm volatile("s_waitcnt vmcnt(0)" ::: "memory");
        }
        __builtin_amdgcn_s_barrier();
#pragma unroll
        for (int ks = 0; ks < 2; ++ks) {
            b16x8 af[4], bf[4];
#pragma unroll
            for (int i = 0; i < 4; ++i) {
                int row = wr * 64 + i * 16 + fr;
                af[i] = *(const b16x8*)&As[cur][row * 64 + (((ks * 4 + fq) ^ (fr & 7)) * 8)];
            }
#pragma unroll
            for (int j = 0; j < 4; ++j) {
                int row = wc * 64 + j * 16 + fr;
                bf[j] = *(const b16x8*)&Bs[cur][row * 64 + (((ks * 4 + fq) ^ (fr & 7)) * 8)];
            }
#pragma unroll
            for (int i = 0; i < 4; ++i)
#pragma unroll
                for (int j = 0; j < 4; ++j)
                    acc[i][j] = __builtin_amdgcn_mfma_f32_16x16x32_bf16(af[i], bf[j], acc[i][j], 0, 0, 0);
        }
        asm volatile("s_waitcnt lgkmcnt(0)" ::: "memory");
        __builtin_amdgcn_s_barrier();
    }
#pragma unroll
    for (int i = 0; i < 4; ++i) {
#pragma unroll
        for (int j = 0; j < 4; ++j) {
            int row = m0 + wr * 64 + i * 16 + fq * 4;
            int col = n0 + wc * 64 + j * 16 + fr;
            float bv = bias ? bias[col] : 0.f;
#pragma unroll
            for (int r = 0; r < 4; ++r) {
                size_t off = (size_t)(row + r) * N + col;
                float v = acc[i][j][r] + bv;
                if (ACCUM) v += C[off];
                if (RELU) v = fmaxf(v, 0.f);
                if (OBF) Cbf[off] = f2bf(v);
                else     C[off] = v;
            }
        }
    }
}

// ---------- GRU gate: t = sig(rp)*x -> tbf (bf16); zp <- sig(zp - bg) in place ----------
__global__ __launch_bounds__(256) void gate_rz_t_kernel(const float* __restrict__ rp, float* __restrict__ zp,
                                                        const float* __restrict__ x, const float* __restrict__ bg,
                                                        u16* __restrict__ tbf) {
    int i = blockIdx.x * 256 + threadIdx.x;
    float4 r4 = ((const float4*)rp)[i];
    float4 z4 = ((const float4*)zp)[i];
    float4 x4 = ((const float4*)x)[i];
    float4 b4 = *(const float4*)&bg[(i & 255) * 4];
    u16 tv[4] = { f2bf(sigmoidf_(r4.x) * x4.x), f2bf(sigmoidf_(r4.y) * x4.y),
                  f2bf(sigmoidf_(r4.z) * x4.z), f2bf(sigmoidf_(r4.w) * x4.w) };
    float4 zz = { sigmoidf_(z4.x - b4.x), sigmoidf_(z4.y - b4.y),
                  sigmoidf_(z4.z - b4.z), sigmoidf_(z4.w - b4.w) };
    ((ushort4*)tbf)[i] = *(ushort4*)tv;
    ((float4*)zp)[i] = zz;
}

// ---------- GRU gate output: out = (1-z)*x + z*tanh(hp); WRH: also bf16 copy ----------
template<int WRH>
__global__ __launch_bounds__(256) void gate_out_kernel(const float* __restrict__ hp, const float* __restrict__ z,
                                                       const float* x, float* outf, u16* __restrict__ hbf) {
    int i = blockIdx.x * 256 + threadIdx.x;
    float4 h4 = ((const float4*)hp)[i];
    float4 z4 = ((const float4*)z)[i];
    float4 x4 = ((const float4*)x)[i];
    float4 o;
    o.x = (1.f - z4.x) * x4.x + z4.x * tanhf(h4.x);
    o.y = (1.f - z4.y) * x4.y + z4.y * tanhf(h4.y);
    o.z = (1.f - z4.z) * x4.z + z4.z * tanhf(h4.z);
    o.w = (1.f - z4.w) * x4.w + z4.w * tanhf(h4.w);
    ((float4*)outf)[i] = o;
    if (WRH) {
        u16 hv[4] = { f2bf(o.x), f2bf(o.y), f2bf(o.z), f2bf(o.w) };
        ((ushort4*)hbf)[i] = *(ushort4*)hv;
    }
}

extern "C" void kernel_launch(void* const* d_in, const int* in_sizes, int n_in,
                              void* d_out, int out_size, void* d_ws, size_t ws_size,
                              hipStream_t stream) {
    const float* value = (const float*)d_in[0];
    // d_in[1] = key (unused: reference sets k_ = normed value)
    const float* query = (const float*)d_in[2];
    const int* mask = (const int*)d_in[3];
    const float* wq = (const float*)d_in[4];
    const float* wk = (const float*)d_in[5];
    const float* wv = (const float*)d_in[6];
    const float* w_out = (const float*)d_in[7];
    const float* b_out = (const float*)d_in[8];
    const float* fc_w = (const float*)d_in[9];
    const float* fc_b = (const float*)d_in[10];
    const float* ln1_s = (const float*)d_in[11];
    const float* ln1_b = (const float*)d_in[12];
    const float* lnkv_s = (const float*)d_in[13];
    const float* lnkv_b = (const float*)d_in[14];
    const float* ln2_s = (const float*)d_in[15];
    const float* ln2_b = (const float*)d_in[16];
    const float* g1_W = (const float*)d_in[17];
    const float* g1_U = (const float*)d_in[18];
    const float* g1_bg = (const float*)d_in[19];
    const float* g2_W = (const float*)d_in[20];
    const float* g2_U = (const float*)d_in[21];
    const float* g2_bg = (const float*)d_in[22];

    float* out_f = (float*)d_out;                     // final out [4096][1024] fp32
    float* attn_f = out_f + (size_t)M_ * D_;          // attn [N,H,L,L] fp32 (256MB)

    // d_out scratch (dead before its region is overwritten by real outputs):
    u16* WA = (u16*)d_out;                            // 7*DD bf16: w_out, g1_W(3), g1_U(3) — dead before h
    float* F0 = attn_f;                               // ln1(q)  — dead before qk writes attn
    float* F1 = attn_f + (size_t)M_ * D_;             // ln(v)
    float* F2 = attn_f + 2 * (size_t)M_ * D_;         // vh fp32
    float* OutH = out_f;                              // h lives in out slice; final gate writes in place

    // ws layout (total 78MB)
    u16* W2 = (u16*)d_ws;                             // 7*DD bf16: fc_w, g2_W(3), g2_U(3)
    float* P0 = (float*)((u16*)d_ws + 7 * (size_t)DD_);   // rp1->hp1->rp2->hp2
    float* P1 = P0 + (size_t)M_ * D_;                 // zp1->zp2
    u16* Q0 = (u16*)(P1 + (size_t)M_ * D_);           // qh -> y -> ln2_bf
    u16* Q1 = Q0 + (size_t)M_ * D_;                   // kh -> query_bf -> f
    u16* Q2 = Q1 + (size_t)M_ * D_;                   // vt -> t1 -> t2
    u16* Q3 = Q2 + (size_t)M_ * D_;                   // o_bf -> h_bf

    const int EW_GRID = (M_ * D_ / 4) / 256;          // 4096
    dim3 gemm_grid(M_ / 128, D_ / 128);               // 32 x 8 = 256 blocks

    // ---- weight conversion (bf16) ----
    cvt_kernel<<<DD_ / 2048, 256, 0, stream>>>(w_out, WA);
    cvt_kernel<<<3 * DD_ / 2048, 256, 0, stream>>>(g1_W, WA + (size_t)DD_);
    cvt_kernel<<<3 * DD_ / 2048, 256, 0, stream>>>(g1_U, WA + 4 * (size_t)DD_);
    cvt_kernel<<<DD_ / 2048, 256, 0, stream>>>(fc_w, W2);
    cvt_kernel<<<3 * DD_ / 2048, 256, 0, stream>>>(g2_W, W2 + (size_t)DD_);
    cvt_kernel<<<3 * DD_ / 2048, 256, 0, stream>>>(g2_U, W2 + 4 * (size_t)DD_);

    // ---- attention ----
    ln_kernel<0><<<M_, 256, 0, stream>>>(query, F0, ln1_s, ln1_b);
    ln_kernel<0><<<M_, 256, 0, stream>>>(value, F1, lnkv_s, lnkv_b);
    proj_kernel<<<M_, 256, 0, stream>>>(F0, F1, wq, wk, wv, Q0, Q1, F2);
    vtrans_kernel<<<dim3(L_ / 64, H_, N_), 256, 0, stream>>>(F2, Q2);
    qk_softmax_kernel<<<dim3(L_ / 32, H_, N_), 512, 0, stream>>>(Q0, Q1, mask, attn_f);
    cvt_kernel<<<M_ * D_ / 2048, 256, 0, stream>>>(query, Q1);          // query_bf (kh dead)
    pv_mfma_kernel<<<dim3(L_ / 128, H_, N_), 256, 0, stream>>>(attn_f, Q2, Q3);
    // o_proj -> y (bf16 only)
    gemm_bf16_kernel<0, 0, 1><<<gemm_grid, 256, 0, stream>>>(Q3, WA, b_out, nullptr, Q0, M_, D_, D_);

    // ---- GRU gate 1 (x = query, y = Q0) ----
    gemm_bf16_kernel<0, 0, 0><<<gemm_grid, 256, 0, stream>>>(Q0, WA + 1 * (size_t)DD_, nullptr, P0, nullptr, M_, D_, D_);
    gemm_bf16_kernel<1, 0, 0><<<gemm_grid, 256, 0, stream>>>(Q1, WA + 4 * (size_t)DD_, nullptr, P0, nullptr, M_, D_, D_);
    gemm_bf16_kernel<0, 0, 0><<<gemm_grid, 256, 0, stream>>>(Q0, WA + 2 * (size_t)DD_, nullptr, P1, nullptr, M_, D_, D_);
    gemm_bf16_kernel<1, 0, 0><<<gemm_grid, 256, 0, stream>>>(Q1, WA + 5 * (size_t)DD_, nullptr, P1, nullptr, M_, D_, D_);
    gate_rz_t_kernel<<<EW_GRID, 256, 0, stream>>>(P0, P1, query, g1_bg, Q2);
    gemm_bf16_kernel<0, 0, 0><<<gemm_grid, 256, 0, stream>>>(Q0, WA + 3 * (size_t)DD_, nullptr, P0, nullptr, M_, D_, D_);
    gemm_bf16_kernel<1, 0, 0><<<gemm_grid, 256, 0, stream>>>(Q2, WA + 6 * (size_t)DD_, nullptr, P0, nullptr, M_, D_, D_);
    gate_out_kernel<1><<<EW_GRID, 256, 0, stream>>>(P0, P1, query, OutH, Q3);   // h -> OutH + h_bf

    // ---- LN2 + FC ----
    ln_kernel<1><<<M_, 256, 0, stream>>>(OutH, Q0, ln2_s, ln2_b);
    gemm_bf16_kernel<0, 1, 1><<<gemm_grid, 256, 0, stream>>>(Q0, W2, fc_b, nullptr, Q1, M_, D_, D_);  // f (ReLU)

    // ---- GRU gate 2 (x = h, y = Q1) ----
    gemm_bf16_kernel<0, 0, 0><<<gemm_grid, 256, 0, stream>>>(Q1, W2 + 1 * (size_t)DD_, nullptr, P0, nullptr, M_, D_, D_);
    gemm_bf16_kernel<1, 0, 0><<<gemm_grid, 256, 0, stream>>>(Q3, W2 + 4 * (size_t)DD_, nullptr, P0, nullptr, M_, D_, D_);
    gemm_bf16_kernel<0, 0, 0><<<gemm_grid, 256, 0, stream>>>(Q1, W2 + 2 * (size_t)DD_, nullptr, P1, nullptr, M_, D_, D_);
    gemm_bf16_kernel<1, 0, 0><<<gemm_grid, 256, 0, stream>>>(Q3, W2 + 5 * (size_t)DD_, nullptr, P1, nullptr, M_, D_, D_);
    gate_rz_t_kernel<<<EW_GRID, 256, 0, stream>>>(P0, P1, OutH, g2_bg, Q2);
    gemm_bf16_kernel<0, 0, 0><<<gemm_grid, 256, 0, stream>>>(Q1, W2 + 3 * (size_t)DD_, nullptr, P0, nullptr, M_, D_, D_);
    gemm_bf16_kernel<1, 0, 0><<<gemm_grid, 256, 0, stream>>>(Q2, W2 + 6 * (size_t)DD_, nullptr, P0, nullptr, M_, D_, D_);
    gate_out_kernel<0><<<EW_GRID, 256, 0, stream>>>(P0, P1, OutH, out_f, nullptr);  // in-place: reads h[i], writes out[i]
}

// Round 7
// 466.082 us; speedup vs baseline: 5.0284x; 1.4426x over previous
//
#include <hip/hip_runtime.h>
#include <cstdint>
#include <cstddef>

#define N_ 4
#define L_ 1024
#define D_ 1024
#define H_ 16
#define HS_ 64
#define M_ (N_*L_)       // 4096 rows
#define DD_ (D_*D_)      // 1048576

typedef unsigned short u16;
typedef __bf16 b16x8 __attribute__((ext_vector_type(8)));
typedef float f32x4 __attribute__((ext_vector_type(4)));

__device__ __forceinline__ float sigmoidf_(float x) { return 1.0f / (1.0f + __expf(-x)); }
__device__ __forceinline__ u16 f2bf(float f) {
    union { float f; uint32_t u; } c; c.f = f;
    uint32_t u = c.u;
    u += 0x7fffu + ((u >> 16) & 1u);   // RNE
    return (u16)(u >> 16);
}

// async global->LDS, 16B per lane
__device__ __forceinline__ void gl_lds16(const void* g, void* l) {
    auto gp = reinterpret_cast<const __attribute__((address_space(1))) unsigned int*>(
        reinterpret_cast<uintptr_t>(g));
    auto lp = reinterpret_cast<__attribute__((address_space(3))) unsigned int*>(
        reinterpret_cast<uintptr_t>(l));
    __builtin_amdgcn_global_load_lds(gp, lp, 16, 0, 0);
}

// ---------------- one-shot weight prep: all bf16 (incl. fused GRU layouts) ----------------
// ws0 layout (u16 elems): Wop[DD] Wfc[DD] WQKV[16384] G1rz[4DD] G1h[2DD] G2rz[4DD] G2h[2DD]
__global__ __launch_bounds__(256) void prep_weights_kernel(
    const float* __restrict__ w_out, const float* __restrict__ fc_w,
    const float* __restrict__ wq, const float* __restrict__ wk, const float* __restrict__ wv,
    const float* __restrict__ g1W, const float* __restrict__ g1U,
    const float* __restrict__ g2W, const float* __restrict__ g2U,
    u16* __restrict__ ws0) {
    u16* Wop = ws0;
    u16* Wfc = ws0 + (size_t)DD_;
    u16* WQKV = ws0 + 2 * (size_t)DD_;
    u16* G1rz = WQKV + 16384;
    u16* G1h = G1rz + 4 * (size_t)DD_;
    u16* G2rz = G1h + 2 * (size_t)DD_;
    u16* G2h = G2rz + 4 * (size_t)DD_;
    int b = blockIdx.x, t = threadIdx.x;
    const float* src; u16* dst; size_t si, di;
    if (b < 512) {
        size_t f = (size_t)b * 2048 + t * 8; src = w_out; si = f; dst = Wop; di = f;
    } else if (b < 1024) {
        size_t f = (size_t)(b - 512) * 2048 + t * 8; src = fc_w; si = f; dst = Wfc; di = f;
    } else if (b < 1030) {
        size_t f = (size_t)(b - 1024) * 2048 + t * 8;
        int which = (int)(f >> 12); size_t off = f & 4095;
        src = which == 0 ? wq : (which == 1 ? wk : wv); si = off; dst = WQKV; di = f;
    } else if (b < 3078) {
        size_t f = (size_t)(b - 1030) * 2048 + t * 8;
        size_t row = f >> 11, k = f & 2047; size_t n2 = (row >= 1024) ? 1 : 0;
        src = (k < 1024) ? (g1W + n2 * DD_) : (g1U + n2 * DD_);
        si = (row & 1023) * 1024 + (k & 1023); dst = G1rz; di = f;
    } else if (b < 4102) {
        size_t f = (size_t)(b - 3078) * 2048 + t * 8;
        size_t row = f >> 11, k = f & 2047;
        src = (k < 1024) ? (g1W + 2 * (size_t)DD_) : (g1U + 2 * (size_t)DD_);
        si = row * 1024 + (k & 1023); dst = G1h; di = f;
    } else if (b < 6150) {
        size_t f = (size_t)(b - 4102) * 2048 + t * 8;
        size_t row = f >> 11, k = f & 2047; size_t n2 = (row >= 1024) ? 1 : 0;
        src = (k < 1024) ? (g2W + n2 * DD_) : (g2U + n2 * DD_);
        si = (row & 1023) * 1024 + (k & 1023); dst = G2rz; di = f;
    } else {
        size_t f = (size_t)(b - 6150) * 2048 + t * 8;
        size_t row = f >> 11, k = f & 2047;
        src = (k < 1024) ? (g2W + 2 * (size_t)DD_) : (g2U + 2 * (size_t)DD_);
        si = row * 1024 + (k & 1023); dst = G2h; di = f;
    }
    float4 a = *(const float4*)&src[si];
    float4 b4 = *(const float4*)&src[si + 4];
    u16 o[8] = { f2bf(a.x), f2bf(a.y), f2bf(a.z), f2bf(a.w),
                 f2bf(b4.x), f2bf(b4.y), f2bf(b4.z), f2bf(b4.w) };
    *(uint4*)&dst[di] = *(uint4*)o;
}

// ---------------- LayerNorm -> bf16 ----------------
__global__ __launch_bounds__(256) void ln_kernel(const float* __restrict__ x, u16* __restrict__ y,
                                                 const float* __restrict__ sc, const float* __restrict__ bi) {
    int row = blockIdx.x;
    const float* xr = x + (size_t)row * D_;
    int t = threadIdx.x;
    float4 v = *(const float4*)&xr[t * 4];
    float s = v.x + v.y + v.z + v.w;
    float q = v.x * v.x + v.y * v.y + v.z * v.z + v.w * v.w;
#pragma unroll
    for (int o = 32; o > 0; o >>= 1) { s += __shfl_xor(s, o); q += __shfl_xor(q, o); }
    __shared__ float ss[4], sq[4];
    int w = t >> 6;
    if ((t & 63) == 0) { ss[w] = s; sq[w] = q; }
    __syncthreads();
    s = ss[0] + ss[1] + ss[2] + ss[3];
    q = sq[0] + sq[1] + sq[2] + sq[3];
    float mean = s * (1.0f / D_);
    float var = q * (1.0f / D_) - mean * mean;
    float inv = rsqrtf(var + 1e-5f);
    float4 sv = *(const float4*)&sc[t * 4];
    float4 bv = *(const float4*)&bi[t * 4];
    u16 ov[4] = { f2bf((v.x - mean) * inv * sv.x + bv.x),
                  f2bf((v.y - mean) * inv * sv.y + bv.y),
                  f2bf((v.z - mean) * inv * sv.z + bv.z),
                  f2bf((v.w - mean) * inv * sv.w + bv.w) };
    *(ushort4*)&y[(size_t)row * D_ + t * 4] = *(ushort4*)ov;
}

// -------- MFMA per-head projections: qh/kh row-major + vt transposed, all bf16 --------
// grid (32 rowblocks, 16 heads); block 256 = 4 waves, wave handles 2 row-tiles of 16.
__global__ __launch_bounds__(256) void proj_mfma_kernel(const u16* __restrict__ qbf,
                                                        const u16* __restrict__ vbf,
                                                        const u16* __restrict__ wqkv,
                                                        u16* __restrict__ qh, u16* __restrict__ kh,
                                                        u16* __restrict__ vt) {
    int t = threadIdx.x, w = t >> 6, l = t & 63;
    int lr = l & 15, lg = l >> 4;
    int rb = blockIdx.x, h = blockIdx.y;
    int n = rb >> 3, lbase = (rb & 7) * 128;
    const u16* wqp = wqkv;
    const u16* wkp = wqkv + 4096;
    const u16* wvp = wqkv + 8192;
    b16x8 wqf[4][2], wkf[4][2], wvf[4][2];
#pragma unroll
    for (int dt = 0; dt < 4; ++dt)
#pragma unroll
        for (int ks = 0; ks < 2; ++ks) {
            int a = (dt * 16 + lr) * 64 + ks * 32 + lg * 8;
            wqf[dt][ks] = *(const b16x8*)&wqp[a];
            wkf[dt][ks] = *(const b16x8*)&wkp[a];
            wvf[dt][ks] = *(const b16x8*)&wvp[a];
        }
#pragma unroll
    for (int rr = 0; rr < 2; ++rr) {
        int rt = w * 2 + rr;
        size_t grow = (size_t)(n * 1024 + lbase + rt * 16 + lr);
        b16x8 aq[2], av[2];
#pragma unroll
        for (int ks = 0; ks < 2; ++ks) {
            aq[ks] = *(const b16x8*)&qbf[grow * D_ + h * 64 + ks * 32 + lg * 8];
            av[ks] = *(const b16x8*)&vbf[grow * D_ + h * 64 + ks * 32 + lg * 8];
        }
#pragma unroll
        for (int dt = 0; dt < 4; ++dt) {
            f32x4 cq = (f32x4){0.f, 0.f, 0.f, 0.f};
            f32x4 ck = (f32x4){0.f, 0.f, 0.f, 0.f};
            f32x4 cv = (f32x4){0.f, 0.f, 0.f, 0.f};
            cq = __builtin_amdgcn_mfma_f32_16x16x32_bf16(aq[0], wqf[dt][0], cq, 0, 0, 0);
            cq = __builtin_amdgcn_mfma_f32_16x16x32_bf16(aq[1], wqf[dt][1], cq, 0, 0, 0);
            ck = __builtin_amdgcn_mfma_f32_16x16x32_bf16(av[0], wkf[dt][0], ck, 0, 0, 0);
            ck = __builtin_amdgcn_mfma_f32_16x16x32_bf16(av[1], wkf[dt][1], ck, 0, 0, 0);
            cv = __builtin_amdgcn_mfma_f32_16x16x32_bf16(wvf[dt][0], av[0], cv, 0, 0, 0);
            cv = __builtin_amdgcn_mfma_f32_16x16x32_bf16(wvf[dt][1], av[1], cv, 0, 0, 0);
#pragma unroll
            for (int r = 0; r < 4; ++r) {
                size_t orow = (size_t)(n * 1024 + lbase + rt * 16 + lg * 4 + r);
                qh[orow * D_ + h * 64 + dt * 16 + lr] = f2bf(cq[r]);
                kh[orow * D_ + h * 64 + dt * 16 + lr] = f2bf(ck[r]);
                vt[((size_t)(n * H_ + h) * 64 + dt * 16 + lg * 4 + r) * L_ + lbase + rt * 16 + lr] = f2bf(cv[r]);
            }
        }
    }
}

// -------- MFMA QK^T + softmax: block = 32 q rows x full L, 8 waves --------
__global__ __launch_bounds__(512, 2) void qk_softmax_kernel(const u16* __restrict__ qh,
                                                            const u16* __restrict__ kh,
                                                            const int* __restrict__ mask,
                                                            float* __restrict__ attn) {
    int t = threadIdx.x;
    int w = t >> 6, l = t & 63;
    int qsub = w & 1, kq = w >> 1;
    int q0 = blockIdx.x * 32;
    int h = blockIdx.y, n = blockIdx.z;
    int lr = l & 15, lg = l >> 4;

    size_t qrow = ((size_t)(n * L_ + q0 + qsub * 16 + lr) * H_ + h) * HS_;
    b16x8 aq0 = *(const b16x8*)&qh[qrow + lg * 8];
    b16x8 aq1 = *(const b16x8*)&qh[qrow + 32 + lg * 8];

    f32x4 c[16];
#pragma unroll
    for (int i = 0; i < 16; ++i) c[i] = (f32x4){0.f, 0.f, 0.f, 0.f};

    size_t kbase = ((size_t)(n * L_ + kq * 256 + lr) * H_ + h) * HS_ + lg * 8;
#pragma unroll
    for (int kt = 0; kt < 16; ++kt) {
        const u16* kp = &kh[kbase + (size_t)kt * 16 * D_];
        b16x8 bk0 = *(const b16x8*)&kp[0];
        b16x8 bk1 = *(const b16x8*)&kp[32];
        c[kt] = __builtin_amdgcn_mfma_f32_16x16x32_bf16(aq0, bk0, c[kt], 0, 0, 0);
        c[kt] = __builtin_amdgcn_mfma_f32_16x16x32_bf16(aq1, bk1, c[kt], 0, 0, 0);
    }

    const float scl = 0.03125f;   // 1/sqrt(1024)
    int kcol = kq * 256 + lr;
    float rowmax[4] = { -1e30f, -1e30f, -1e30f, -1e30f };
#pragma unroll
    for (int kt = 0; kt < 16; ++kt) {
        int mk = mask[n * L_ + kcol + kt * 16];
#pragma unroll
        for (int r = 0; r < 4; ++r) {
            float s = (mk != 0) ? c[kt][r] * scl : -1e20f;
            c[kt][r] = s;
            rowmax[r] = fmaxf(rowmax[r], s);
        }
    }
#pragma unroll
    for (int o = 8; o > 0; o >>= 1)
#pragma unroll
        for (int r = 0; r < 4; ++r) rowmax[r] = fmaxf(rowmax[r], __shfl_xor(rowmax[r], o));

    __shared__ float redA[32][4];
    __shared__ float redB[32][4];
    int qrow4 = qsub * 16 + lg * 4;
    if (lr == 0) {
#pragma unroll
        for (int r = 0; r < 4; ++r) redA[qrow4 + r][kq] = rowmax[r];
    }
    __syncthreads();
#pragma unroll
    for (int r = 0; r < 4; ++r)
        rowmax[r] = fmaxf(fmaxf(redA[qrow4 + r][0], redA[qrow4 + r][1]),
                          fmaxf(redA[qrow4 + r][2], redA[qrow4 + r][3]));
    float rowsum[4] = { 0.f, 0.f, 0.f, 0.f };
#pragma unroll
    for (int kt = 0; kt < 16; ++kt)
#pragma unroll
        for (int r = 0; r < 4; ++r) {
            float e = __expf(c[kt][r] - rowmax[r]);
            c[kt][r] = e;
            rowsum[r] += e;
        }
#pragma unroll
    for (int o = 8; o > 0; o >>= 1)
#pragma unroll
        for (int r = 0; r < 4; ++r) rowsum[r] += __shfl_xor(rowsum[r], o);
    if (lr == 0) {
#pragma unroll
        for (int r = 0; r < 4; ++r) redB[qrow4 + r][kq] = rowsum[r];
    }
    __syncthreads();
    float inv[4];
#pragma unroll
    for (int r = 0; r < 4; ++r)
        inv[r] = 1.0f / (redB[qrow4 + r][0] + redB[qrow4 + r][1] +
                         redB[qrow4 + r][2] + redB[qrow4 + r][3]);

    float* ap = attn + ((size_t)((n * H_ + h) * L_) + q0 + qrow4) * L_ + kcol;
#pragma unroll
    for (int kt = 0; kt < 16; ++kt)
#pragma unroll
        for (int r = 0; r < 4; ++r)
            ap[(size_t)r * L_ + kt * 16] = c[kt][r] * inv[r];
}

// -------- MFMA PV: O^T[d][q] per (n,h); output bf16 [n,q,h,d] --------
#define PLD 40
__global__ __launch_bounds__(256) void pv_mfma_kernel(const float* __restrict__ attn,
                                                      const u16* __restrict__ vt,
                                                      u16* __restrict__ o) {
    __shared__ u16 a_lds[128 * PLD];
    __shared__ u16 v_lds[64 * PLD];
    int t = threadIdx.x, w = t >> 6, l = t & 63;
    int lr = l & 15, lg = l >> 4;
    int qb = blockIdx.x * 128, h = blockIdx.y, n = blockIdx.z;
    const float* abase = attn + ((size_t)((n * H_ + h) * L_) + qb) * L_;
    const u16* vbase = vt + (size_t)(n * H_ + h) * HS_ * L_;
    f32x4 acc[4][2];
#pragma unroll
    for (int i = 0; i < 4; ++i)
#pragma unroll
        for (int j = 0; j < 2; ++j) acc[i][j] = (f32x4){0.f, 0.f, 0.f, 0.f};

    int sq = t >> 1, sk = (t & 1) * 16;
    int vd = t >> 2, vk = (t & 3) * 8;
    for (int kb = 0; kb < L_; kb += 32) {
        float va[16];
#pragma unroll
        for (int i = 0; i < 4; ++i)
            *(float4*)&va[i * 4] = *(const float4*)&abase[(size_t)sq * L_ + kb + sk + i * 4];
        b16x8 vv = *(const b16x8*)&vbase[(size_t)vd * L_ + kb + vk];
        u16 ua[16];
#pragma unroll
        for (int i = 0; i < 16; ++i) ua[i] = f2bf(va[i]);
        __syncthreads();
        *(uint4*)&a_lds[sq * PLD + sk] = *(uint4*)&ua[0];
        *(uint4*)&a_lds[sq * PLD + sk + 8] = *(uint4*)&ua[8];
        *(b16x8*)&v_lds[vd * PLD + vk] = vv;
        __syncthreads();
        b16x8 bq[2];
#pragma unroll
        for (int qt = 0; qt < 2; ++qt)
            bq[qt] = *(const b16x8*)&a_lds[(w * 32 + qt * 16 + lr) * PLD + lg * 8];
#pragma unroll
        for (int dt = 0; dt < 4; ++dt) {
            b16x8 av = *(const b16x8*)&v_lds[(dt * 16 + lr) * PLD + lg * 8];
#pragma unroll
            for (int qt = 0; qt < 2; ++qt)
                acc[dt][qt] = __builtin_amdgcn_mfma_f32_16x16x32_bf16(av, bq[qt], acc[dt][qt], 0, 0, 0);
        }
    }
#pragma unroll
    for (int dt = 0; dt < 4; ++dt)
#pragma unroll
        for (int qt = 0; qt < 2; ++qt) {
            int q = qb + w * 32 + qt * 16 + lr;
            int d = dt * 16 + lg * 4;
            u16 ov[4] = { f2bf(acc[dt][qt][0]), f2bf(acc[dt][qt][1]),
                          f2bf(acc[dt][qt][2]), f2bf(acc[dt][qt][3]) };
            *(ushort4*)&o[((size_t)(n * L_ + q) * H_ + h) * HS_ + d] = *(ushort4*)ov;
        }
}

// ---------- bf16 GEMM: C[M,N] = A[M,K] @ B[N,K]^T (+bias)(ReLU) ----------
// 128x128 tile, 4 waves, BK=64, dbuf global_load_lds w16, counted vmcnt, XOR-swizzled LDS.
// Epilogue: Cbf!=null -> bf16 out at ldc; else fp32 split at col 1024 -> C0/C1 (stride 1024).
__global__ __launch_bounds__(256) void gemm_bf16_kernel(const u16* __restrict__ A, int lda,
                                                        const u16* __restrict__ Bw, int ldb,
                                                        const float* __restrict__ bias,
                                                        float* __restrict__ C0, float* __restrict__ C1,
                                                        u16* __restrict__ Cbf, int ldc,
                                                        int K, int relu) {
    __shared__ u16 As[2][128 * 64];
    __shared__ u16 Bs[2][128 * 64];
    int t = threadIdx.x, w = t >> 6, l = t & 63;
    int wr = w >> 1, wc = w & 1;
    int m0 = blockIdx.x * 128, n0 = blockIdx.y * 128;
    int fr = l & 15, fq = l >> 4;
    int srow = l >> 3;
    int gc8 = (l & 7) ^ (srow & 7);
    const u16* Abase = A + (size_t)m0 * lda;
    const u16* Bbase = Bw + (size_t)n0 * ldb;

    f32x4 acc[4][4];
#pragma unroll
    for (int i = 0; i < 4; ++i)
#pragma unroll
        for (int j = 0; j < 4; ++j) acc[i][j] = (f32x4){0.f, 0.f, 0.f, 0.f};

    auto STAGE = [&](int buf, int kk) {
#pragma unroll
        for (int i = 0; i < 4; ++i) {
            int r0 = (i * 4 + w) * 8;
            gl_lds16(&Abase[(size_t)(r0 + srow) * lda + kk + gc8 * 8], &As[buf][r0 * 64]);
            gl_lds16(&Bbase[(size_t)(r0 + srow) * ldb + kk + gc8 * 8], &Bs[buf][r0 * 64]);
        }
    };
    STAGE(0, 0);
    const int NT = K >> 6;
    for (int kt = 0; kt < NT; ++kt) {
        int cur = kt & 1;
        if (kt + 1 < NT) {
            STAGE(cur ^ 1, (kt + 1) << 6);
            asm volatile("s_waitcnt vmcnt(8)" ::: "memory");
        } else {
            asm volatile("s_waitcnt vmcnt(0)" ::: "memory");
        }
        __builtin_amdgcn_s_barrier();
#pragma unroll
        for (int ks = 0; ks < 2; ++ks) {
            b16x8 af[4], bf[4];
#pragma unroll
            for (int i = 0; i < 4; ++i) {
                int row = wr * 64 + i * 16 + fr;
                af[i] = *(const b16x8*)&As[cur][row * 64 + (((ks * 4 + fq) ^ (fr & 7)) * 8)];
            }
#pragma unroll
            for (int j = 0; j < 4; ++j) {
                int row = wc * 64 + j * 16 + fr;
                bf[j] = *(const b16x8*)&Bs[cur][row * 64 + (((ks * 4 + fq) ^ (fr & 7)) * 8)];
            }
#pragma unroll
            for (int i = 0; i < 4; ++i)
#pragma unroll
                for (int j = 0; j < 4; ++j)
                    acc[i][j] = __builtin_amdgcn_mfma_f32_16x16x32_bf16(af[i], bf[j], acc[i][j], 0, 0, 0);
        }
        asm volatile("s_waitcnt lgkmcnt(0)" ::: "memory");
        __builtin_amdgcn_s_barrier();
    }
#pragma unroll
    for (int i = 0; i < 4; ++i) {
#pragma unroll
        for (int j = 0; j < 4; ++j) {
            int row = m0 + wr * 64 + i * 16 + fq * 4;
            int col = n0 + wc * 64 + j * 16 + fr;
            float bv = bias ? bias[col] : 0.f;
#pragma unroll
            for (int r = 0; r < 4; ++r) {
                float v = acc[i][j][r] + bv;
                if (relu) v = fmaxf(v, 0.f);
                if (Cbf) {
                    Cbf[(size_t)(row + r) * ldc + col] = f2bf(v);
                } else {
                    float* dst = (col < 1024) ? C0 : C1;
                    dst[(size_t)(row + r) * 1024 + (col & 1023)] = v;
                }
            }
        }
    }
}

// ---------- GRU gate: t = sig(rp)*x -> A1 right half (bf16, stride 2048); zp <- sig(zp-bg) ----------
__global__ __launch_bounds__(256) void gate_rz_t_kernel(const float* __restrict__ rp, float* __restrict__ zp,
                                                        const float* __restrict__ x, const float* __restrict__ bg,
                                                        u16* __restrict__ tbf) {
    int i = blockIdx.x * 256 + threadIdx.x;
    float4 r4 = ((const float4*)rp)[i];
    float4 z4 = ((const float4*)zp)[i];
    float4 x4 = ((const float4*)x)[i];
    float4 b4 = *(const float4*)&bg[(i & 255) * 4];
    u16 tv[4] = { f2bf(sigmoidf_(r4.x) * x4.x), f2bf(sigmoidf_(r4.y) * x4.y),
                  f2bf(sigmoidf_(r4.z) * x4.z), f2bf(sigmoidf_(r4.w) * x4.w) };
    float4 zz = { sigmoidf_(z4.x - b4.x), sigmoidf_(z4.y - b4.y),
                  sigmoidf_(z4.z - b4.z), sigmoidf_(z4.w - b4.w) };
    size_t f = (size_t)i * 4;
    size_t row = f >> 10, col = f & 1023;
    *(ushort4*)&tbf[row * 2048 + 1024 + col] = *(ushort4*)tv;
    ((float4*)zp)[i] = zz;
}

// ---------- GRU gate output: out = (1-z)*x + z*tanh(hp); WRH: bf16 copy into A1 right half ----------
template<int WRH>
__global__ __launch_bounds__(256) void gate_out_kernel(const float* __restrict__ hp, const float* __restrict__ z,
                                                       const float* x, float* outf, u16* __restrict__ hbf) {
    int i = blockIdx.x * 256 + threadIdx.x;
    float4 h4 = ((const float4*)hp)[i];
    float4 z4 = ((const float4*)z)[i];
    float4 x4 = ((const float4*)x)[i];
    float4 o;
    o.x = (1.f - z4.x) * x4.x + z4.x * tanhf(h4.x);
    o.y = (1.f - z4.y) * x4.y + z4.y * tanhf(h4.y);
    o.z = (1.f - z4.z) * x4.z + z4.z * tanhf(h4.z);
    o.w = (1.f - z4.w) * x4.w + z4.w * tanhf(h4.w);
    ((float4*)outf)[i] = o;
    if (WRH) {
        u16 hv[4] = { f2bf(o.x), f2bf(o.y), f2bf(o.z), f2bf(o.w) };
        size_t f = (size_t)i * 4;
        size_t row = f >> 10, col = f & 1023;
        *(ushort4*)&hbf[row * 2048 + 1024 + col] = *(ushort4*)hv;
    }
}

// ---------- query fp32 -> bf16 into A1 right half (stride 2048) ----------
__global__ __launch_bounds__(256) void cvtq_kernel(const float* __restrict__ src, u16* __restrict__ dst) {
    size_t f = ((size_t)blockIdx.x * 256 + threadIdx.x) * 8;
    float4 a = *(const float4*)&src[f];
    float4 b = *(const float4*)&src[f + 4];
    u16 o[8] = { f2bf(a.x), f2bf(a.y), f2bf(a.z), f2bf(a.w),
                 f2bf(b.x), f2bf(b.y), f2bf(b.z), f2bf(b.w) };
    size_t row = f >> 10, col = f & 1023;
    *(uint4*)&dst[row * 2048 + 1024 + col] = *(uint4*)o;
}

extern "C" void kernel_launch(void* const* d_in, const int* in_sizes, int n_in,
                              void* d_out, int out_size, void* d_ws, size_t ws_size,
                              hipStream_t stream) {
    const float* value = (const float*)d_in[0];
    // d_in[1] = key (unused: reference sets k_ = normed value)
    const float* query = (const float*)d_in[2];
    const int* mask = (const int*)d_in[3];
    const float* wq = (const float*)d_in[4];
    const float* wk = (const float*)d_in[5];
    const float* wv = (const float*)d_in[6];
    const float* w_out = (const float*)d_in[7];
    const float* b_out = (const float*)d_in[8];
    const float* fc_w = (const float*)d_in[9];
    const float* fc_b = (const float*)d_in[10];
    const float* ln1_s = (const float*)d_in[11];
    const float* ln1_b = (const float*)d_in[12];
    const float* lnkv_s = (const float*)d_in[13];
    const float* lnkv_b = (const float*)d_in[14];
    const float* ln2_s = (const float*)d_in[15];
    const float* ln2_b = (const float*)d_in[16];
    const float* g1_W = (const float*)d_in[17];
    const float* g1_U = (const float*)d_in[18];
    const float* g1_bg = (const float*)d_in[19];
    const float* g2_W = (const float*)d_in[20];
    const float* g2_U = (const float*)d_in[21];
    const float* g2_bg = (const float*)d_in[22];

    float* out_f = (float*)d_out;                     // final out [4096][1024] fp32
    float* attn_f = out_f + (size_t)M_ * D_;          // attn [N,H,L,L] fp32 (output 1)
    float* OutH = out_f;                              // h lives in out slice; final gate in-place

    // ---- d_ws layout (u16 units) ----
    u16* WS = (u16*)d_ws;
    u16* Wop = WS;                                    // DD
    u16* Wfc = WS + (size_t)DD_;                      // DD
    u16* WQKV = WS + 2 * (size_t)DD_;                 // 16384 (12288 used)
    u16* G1rz = WQKV + 16384;                         // 4DD
    u16* G1h  = G1rz + 4 * (size_t)DD_;               // 2DD
    u16* G2rz = G1h + 2 * (size_t)DD_;                // 4DD
    u16* G2h  = G2rz + 4 * (size_t)DD_;               // 2DD
    u16* A1   = G2h + 2 * (size_t)DD_;                // [4096][2048] bf16
    float* P0 = (float*)(A1 + 8 * (size_t)DD_ / 1);   // A1 = 8M u16
    P0 = (float*)(A1 + (size_t)M_ * 2048);
    float* P1 = P0 + (size_t)M_ * D_;
    u16* QH  = (u16*)(P1 + (size_t)M_ * D_);
    u16* KH  = QH + (size_t)M_ * D_;
    u16* VT  = KH + (size_t)M_ * D_;
    u16* OBF = VT + (size_t)M_ * D_;
    u16* LNQ = OBF + (size_t)M_ * D_;
    u16* LNV = LNQ + (size_t)M_ * D_;
    u16* LN2 = LNV + (size_t)M_ * D_;

    const int EW_GRID = (M_ * D_ / 4) / 256;          // 4096
    dim3 grid_n1024(M_ / 128, 8);                     // 256 blocks
    dim3 grid_n2048(M_ / 128, 16);                    // 512 blocks

    // ---- weight prep (1 launch) ----
    prep_weights_kernel<<<7174, 256, 0, stream>>>(w_out, fc_w, wq, wk, wv,
                                                  g1_W, g1_U, g2_W, g2_U, WS);

    // ---- attention ----
    ln_kernel<<<M_, 256, 0, stream>>>(query, LNQ, ln1_s, ln1_b);
    ln_kernel<<<M_, 256, 0, stream>>>(value, LNV, lnkv_s, lnkv_b);
    proj_mfma_kernel<<<dim3(32, 16), 256, 0, stream>>>(LNQ, LNV, WQKV, QH, KH, VT);
    qk_softmax_kernel<<<dim3(L_ / 32, H_, N_), 512, 0, stream>>>(QH, KH, mask, attn_f);
    cvtq_kernel<<<M_ * D_ / 2048, 256, 0, stream>>>(query, A1);   // x -> A1 right half
    pv_mfma_kernel<<<dim3(L_ / 128, H_, N_), 256, 0, stream>>>(attn_f, VT, OBF);
    // o_proj: y -> A1 left half (bf16)
    gemm_bf16_kernel<<<grid_n1024, 256, 0, stream>>>(OBF, 1024, Wop, 1024, b_out,
                                                     nullptr, nullptr, A1, 2048, 1024, 0);

    // ---- GRU gate 1: [rp|zp] = [y|x] @ G1rz^T ----
    gemm_bf16_kernel<<<grid_n2048, 256, 0, stream>>>(A1, 2048, G1rz, 2048, nullptr,
                                                     P0, P1, nullptr, 0, 2048, 0);
    gate_rz_t_kernel<<<EW_GRID, 256, 0, stream>>>(P0, P1, query, g1_bg, A1);
    gemm_bf16_kernel<<<grid_n1024, 256, 0, stream>>>(A1, 2048, G1h, 2048, nullptr,
                                                     P0, nullptr, nullptr, 0, 2048, 0);
    gate_out_kernel<1><<<EW_GRID, 256, 0, stream>>>(P0, P1, query, OutH, A1);   // h + h_bf

    // ---- LN2 + FC ----
    ln_kernel<<<M_, 256, 0, stream>>>(OutH, LN2, ln2_s, ln2_b);
    gemm_bf16_kernel<<<grid_n1024, 256, 0, stream>>>(LN2, 1024, Wfc, 1024, fc_b,
                                                     nullptr, nullptr, A1, 2048, 1024, 1);  // f (ReLU)

    // ---- GRU gate 2: [rp|zp] = [f|h] @ G2rz^T ----
    gemm_bf16_kernel<<<grid_n2048, 256, 0, stream>>>(A1, 2048, G2rz, 2048, nullptr,
                                                     P0, P1, nullptr, 0, 2048, 0);
    gate_rz_t_kernel<<<EW_GRID, 256, 0, stream>>>(P0, P1, OutH, g2_bg, A1);
    gemm_bf16_kernel<<<grid_n1024, 256, 0, stream>>>(A1, 2048, G2h, 2048, nullptr,
                                                     P0, nullptr, nullptr, 0, 2048, 0);
    gate_out_kernel<0><<<EW_GRID, 256, 0, stream>>>(P0, P1, OutH, out_f, nullptr);
}

// Round 8
// 441.139 us; speedup vs baseline: 5.3127x; 1.0565x over previous
//
#include <hip/hip_runtime.h>
#include <cstdint>
#include <cstddef>

#define N_ 4
#define L_ 1024
#define D_ 1024
#define H_ 16
#define HS_ 64
#define M_ (N_*L_)       // 4096 rows
#define DD_ (D_*D_)      // 1048576
#define MD_ ((size_t)M_*D_)

typedef unsigned short u16;
typedef __bf16 b16x8 __attribute__((ext_vector_type(8)));
typedef float f32x4 __attribute__((ext_vector_type(4)));

__device__ __forceinline__ float sigmoidf_(float x) { return 1.0f / (1.0f + __expf(-x)); }
__device__ __forceinline__ u16 f2bf(float f) {
    union { float f; uint32_t u; } c; c.f = f;
    uint32_t u = c.u;
    u += 0x7fffu + ((u >> 16) & 1u);   // RNE
    return (u16)(u >> 16);
}

// async global->LDS, 16B per lane
__device__ __forceinline__ void gl_lds16(const void* g, void* l) {
    auto gp = reinterpret_cast<const __attribute__((address_space(1))) unsigned int*>(
        reinterpret_cast<uintptr_t>(g));
    auto lp = reinterpret_cast<__attribute__((address_space(3))) unsigned int*>(
        reinterpret_cast<uintptr_t>(l));
    __builtin_amdgcn_global_load_lds(gp, lp, 16, 0, 0);
}

// ---------------- one-shot weight prep: all bf16 (incl. fused GRU layouts) ----------------
// ws0 layout (u16): Wop[DD] Wfc[DD] WQKV[16384] G1rz[4DD] G1h[2DD] G2rz[4DD] G2h[2DD]
__global__ __launch_bounds__(256) void prep_weights_kernel(
    const float* __restrict__ w_out, const float* __restrict__ fc_w,
    const float* __restrict__ wq, const float* __restrict__ wk, const float* __restrict__ wv,
    const float* __restrict__ g1W, const float* __restrict__ g1U,
    const float* __restrict__ g2W, const float* __restrict__ g2U,
    u16* __restrict__ ws0) {
    u16* Wop = ws0;
    u16* Wfc = ws0 + (size_t)DD_;
    u16* WQKV = ws0 + 2 * (size_t)DD_;
    u16* G1rz = WQKV + 16384;
    u16* G1h = G1rz + 4 * (size_t)DD_;
    u16* G2rz = G1h + 2 * (size_t)DD_;
    u16* G2h = G2rz + 4 * (size_t)DD_;
    int b = blockIdx.x, t = threadIdx.x;
    const float* src; u16* dst; size_t si, di;
    if (b < 512) {
        size_t f = (size_t)b * 2048 + t * 8; src = w_out; si = f; dst = Wop; di = f;
    } else if (b < 1024) {
        size_t f = (size_t)(b - 512) * 2048 + t * 8; src = fc_w; si = f; dst = Wfc; di = f;
    } else if (b < 1030) {
        size_t f = (size_t)(b - 1024) * 2048 + t * 8;
        int which = (int)(f >> 12); size_t off = f & 4095;
        src = which == 0 ? wq : (which == 1 ? wk : wv); si = off; dst = WQKV; di = f;
    } else if (b < 3078) {
        size_t f = (size_t)(b - 1030) * 2048 + t * 8;
        size_t row = f >> 11, k = f & 2047; size_t n2 = (row >= 1024) ? 1 : 0;
        src = (k < 1024) ? (g1W + n2 * DD_) : (g1U + n2 * DD_);
        si = (row & 1023) * 1024 + (k & 1023); dst = G1rz; di = f;
    } else if (b < 4102) {
        size_t f = (size_t)(b - 3078) * 2048 + t * 8;
        size_t row = f >> 11, k = f & 2047;
        src = (k < 1024) ? (g1W + 2 * (size_t)DD_) : (g1U + 2 * (size_t)DD_);
        si = row * 1024 + (k & 1023); dst = G1h; di = f;
    } else if (b < 6150) {
        size_t f = (size_t)(b - 4102) * 2048 + t * 8;
        size_t row = f >> 11, k = f & 2047; size_t n2 = (row >= 1024) ? 1 : 0;
        src = (k < 1024) ? (g2W + n2 * DD_) : (g2U + n2 * DD_);
        si = (row & 1023) * 1024 + (k & 1023); dst = G2rz; di = f;
    } else {
        size_t f = (size_t)(b - 6150) * 2048 + t * 8;
        size_t row = f >> 11, k = f & 2047;
        src = (k < 1024) ? (g2W + 2 * (size_t)DD_) : (g2U + 2 * (size_t)DD_);
        si = row * 1024 + (k & 1023); dst = G2h; di = f;
    }
    float4 a = *(const float4*)&src[si];
    float4 b4 = *(const float4*)&src[si + 4];
    u16 o[8] = { f2bf(a.x), f2bf(a.y), f2bf(a.z), f2bf(a.w),
                 f2bf(b4.x), f2bf(b4.y), f2bf(b4.z), f2bf(b4.w) };
    *(uint4*)&dst[di] = *(uint4*)o;
}

// ---------------- LayerNorm -> bf16 ----------------
__global__ __launch_bounds__(256) void ln_kernel(const float* __restrict__ x, u16* __restrict__ y,
                                                 const float* __restrict__ sc, const float* __restrict__ bi) {
    int row = blockIdx.x;
    const float* xr = x + (size_t)row * D_;
    int t = threadIdx.x;
    float4 v = *(const float4*)&xr[t * 4];
    float s = v.x + v.y + v.z + v.w;
    float q = v.x * v.x + v.y * v.y + v.z * v.z + v.w * v.w;
#pragma unroll
    for (int o = 32; o > 0; o >>= 1) { s += __shfl_xor(s, o); q += __shfl_xor(q, o); }
    __shared__ float ss[4], sq[4];
    int w = t >> 6;
    if ((t & 63) == 0) { ss[w] = s; sq[w] = q; }
    __syncthreads();
    s = ss[0] + ss[1] + ss[2] + ss[3];
    q = sq[0] + sq[1] + sq[2] + sq[3];
    float mean = s * (1.0f / D_);
    float var = q * (1.0f / D_) - mean * mean;
    float inv = rsqrtf(var + 1e-5f);
    float4 sv = *(const float4*)&sc[t * 4];
    float4 bv = *(const float4*)&bi[t * 4];
    u16 ov[4] = { f2bf((v.x - mean) * inv * sv.x + bv.x),
                  f2bf((v.y - mean) * inv * sv.y + bv.y),
                  f2bf((v.z - mean) * inv * sv.z + bv.z),
                  f2bf((v.w - mean) * inv * sv.w + bv.w) };
    *(ushort4*)&y[(size_t)row * D_ + t * 4] = *(ushort4*)ov;
}

// ---------- query fp32 -> bf16 flat ----------
__global__ __launch_bounds__(256) void cvtq_kernel(const float* __restrict__ src, u16* __restrict__ dst) {
    size_t f = ((size_t)blockIdx.x * 256 + threadIdx.x) * 8;
    float4 a = *(const float4*)&src[f];
    float4 b = *(const float4*)&src[f + 4];
    u16 o[8] = { f2bf(a.x), f2bf(a.y), f2bf(a.z), f2bf(a.w),
                 f2bf(b.x), f2bf(b.y), f2bf(b.z), f2bf(b.w) };
    *(uint4*)&dst[f] = *(uint4*)o;
}

// -------- MFMA per-head projections: qh/kh row-major + vt transposed, all bf16 --------
__global__ __launch_bounds__(256) void proj_mfma_kernel(const u16* __restrict__ qbf,
                                                        const u16* __restrict__ vbf,
                                                        const u16* __restrict__ wqkv,
                                                        u16* __restrict__ qh, u16* __restrict__ kh,
                                                        u16* __restrict__ vt) {
    int t = threadIdx.x, w = t >> 6, l = t & 63;
    int lr = l & 15, lg = l >> 4;
    int rb = blockIdx.x, h = blockIdx.y;
    int n = rb >> 3, lbase = (rb & 7) * 128;
    const u16* wqp = wqkv;
    const u16* wkp = wqkv + 4096;
    const u16* wvp = wqkv + 8192;
    b16x8 wqf[4][2], wkf[4][2], wvf[4][2];
#pragma unroll
    for (int dt = 0; dt < 4; ++dt)
#pragma unroll
        for (int ks = 0; ks < 2; ++ks) {
            int a = (dt * 16 + lr) * 64 + ks * 32 + lg * 8;
            wqf[dt][ks] = *(const b16x8*)&wqp[a];
            wkf[dt][ks] = *(const b16x8*)&wkp[a];
            wvf[dt][ks] = *(const b16x8*)&wvp[a];
        }
#pragma unroll
    for (int rr = 0; rr < 2; ++rr) {
        int rt = w * 2 + rr;
        size_t grow = (size_t)(n * 1024 + lbase + rt * 16 + lr);
        b16x8 aq[2], av[2];
#pragma unroll
        for (int ks = 0; ks < 2; ++ks) {
            aq[ks] = *(const b16x8*)&qbf[grow * D_ + h * 64 + ks * 32 + lg * 8];
            av[ks] = *(const b16x8*)&vbf[grow * D_ + h * 64 + ks * 32 + lg * 8];
        }
#pragma unroll
        for (int dt = 0; dt < 4; ++dt) {
            f32x4 cq = (f32x4){0.f, 0.f, 0.f, 0.f};
            f32x4 ck = (f32x4){0.f, 0.f, 0.f, 0.f};
            f32x4 cv = (f32x4){0.f, 0.f, 0.f, 0.f};
            cq = __builtin_amdgcn_mfma_f32_16x16x32_bf16(aq[0], wqf[dt][0], cq, 0, 0, 0);
            cq = __builtin_amdgcn_mfma_f32_16x16x32_bf16(aq[1], wqf[dt][1], cq, 0, 0, 0);
            ck = __builtin_amdgcn_mfma_f32_16x16x32_bf16(av[0], wkf[dt][0], ck, 0, 0, 0);
            ck = __builtin_amdgcn_mfma_f32_16x16x32_bf16(av[1], wkf[dt][1], ck, 0, 0, 0);
            cv = __builtin_amdgcn_mfma_f32_16x16x32_bf16(wvf[dt][0], av[0], cv, 0, 0, 0);
            cv = __builtin_amdgcn_mfma_f32_16x16x32_bf16(wvf[dt][1], av[1], cv, 0, 0, 0);
#pragma unroll
            for (int r = 0; r < 4; ++r) {
                size_t orow = (size_t)(n * 1024 + lbase + rt * 16 + lg * 4 + r);
                qh[orow * D_ + h * 64 + dt * 16 + lr] = f2bf(cq[r]);
                kh[orow * D_ + h * 64 + dt * 16 + lr] = f2bf(ck[r]);
                vt[((size_t)(n * H_ + h) * 64 + dt * 16 + lg * 4 + r) * L_ + lbase + rt * 16 + lr] = f2bf(cv[r]);
            }
        }
    }
}

// -------- fused MFMA QK^T + softmax + PV: block = 32 q x full L, 8 waves --------
// QK: wave (qsub,kq) computes S[16q][256k]. P staged bf16 in LDS. PV: wave (qsub,dg)
// computes O[16q][16d] over K=1024 (A=P from LDS, B=V^T from global).
#define PSTR 1032
__global__ __launch_bounds__(512, 4) void qk_pv_kernel(const u16* __restrict__ qh,
                                                       const u16* __restrict__ kh,
                                                       const u16* __restrict__ vt,
                                                       const int* __restrict__ mask,
                                                       float* __restrict__ attn,
                                                       u16* __restrict__ obf) {
    __shared__ u16 P_lds[32 * PSTR];       // 66KB
    __shared__ float redA[32][4];
    __shared__ float redB[32][4];
    int t = threadIdx.x;
    int w = t >> 6, l = t & 63;
    int qsub = w & 1, kq = w >> 1;
    int q0 = blockIdx.x * 32;
    int h = blockIdx.y, n = blockIdx.z;
    int lr = l & 15, lg = l >> 4;

    size_t qrow = ((size_t)(n * L_ + q0 + qsub * 16 + lr) * H_ + h) * HS_;
    b16x8 aq0 = *(const b16x8*)&qh[qrow + lg * 8];
    b16x8 aq1 = *(const b16x8*)&qh[qrow + 32 + lg * 8];

    f32x4 c[16];
#pragma unroll
    for (int i = 0; i < 16; ++i) c[i] = (f32x4){0.f, 0.f, 0.f, 0.f};

    size_t kbase = ((size_t)(n * L_ + kq * 256 + lr) * H_ + h) * HS_ + lg * 8;
#pragma unroll
    for (int kt = 0; kt < 16; ++kt) {
        const u16* kp = &kh[kbase + (size_t)kt * 16 * D_];
        b16x8 bk0 = *(const b16x8*)&kp[0];
        b16x8 bk1 = *(const b16x8*)&kp[32];
        c[kt] = __builtin_amdgcn_mfma_f32_16x16x32_bf16(aq0, bk0, c[kt], 0, 0, 0);
        c[kt] = __builtin_amdgcn_mfma_f32_16x16x32_bf16(aq1, bk1, c[kt], 0, 0, 0);
    }

    const float scl = 0.03125f;   // 1/sqrt(1024)
    int kcol = kq * 256 + lr;
    float rowmax[4] = { -1e30f, -1e30f, -1e30f, -1e30f };
#pragma unroll
    for (int kt = 0; kt < 16; ++kt) {
        int mk = mask[n * L_ + kcol + kt * 16];
#pragma unroll
        for (int r = 0; r < 4; ++r) {
            float s = (mk != 0) ? c[kt][r] * scl : -1e20f;
            c[kt][r] = s;
            rowmax[r] = fmaxf(rowmax[r], s);
        }
    }
#pragma unroll
    for (int o = 8; o > 0; o >>= 1)
#pragma unroll
        for (int r = 0; r < 4; ++r) rowmax[r] = fmaxf(rowmax[r], __shfl_xor(rowmax[r], o));

    int qrow4 = qsub * 16 + lg * 4;
    if (lr == 0) {
#pragma unroll
        for (int r = 0; r < 4; ++r) redA[qrow4 + r][kq] = rowmax[r];
    }
    __syncthreads();
#pragma unroll
    for (int r = 0; r < 4; ++r)
        rowmax[r] = fmaxf(fmaxf(redA[qrow4 + r][0], redA[qrow4 + r][1]),
                          fmaxf(redA[qrow4 + r][2], redA[qrow4 + r][3]));
    float rowsum[4] = { 0.f, 0.f, 0.f, 0.f };
#pragma unroll
    for (int kt = 0; kt < 16; ++kt)
#pragma unroll
        for (int r = 0; r < 4; ++r) {
            float e = __expf(c[kt][r] - rowmax[r]);
            c[kt][r] = e;
            rowsum[r] += e;
        }
#pragma unroll
    for (int o = 8; o > 0; o >>= 1)
#pragma unroll
        for (int r = 0; r < 4; ++r) rowsum[r] += __shfl_xor(rowsum[r], o);
    if (lr == 0) {
#pragma unroll
        for (int r = 0; r < 4; ++r) redB[qrow4 + r][kq] = rowsum[r];
    }
    __syncthreads();
    float inv[4];
#pragma unroll
    for (int r = 0; r < 4; ++r)
        inv[r] = 1.0f / (redB[qrow4 + r][0] + redB[qrow4 + r][1] +
                         redB[qrow4 + r][2] + redB[qrow4 + r][3]);

    // write attn fp32 (mandatory output) + stage P bf16 into LDS
    float* ap = attn + ((size_t)((n * H_ + h) * L_) + q0 + qrow4) * L_ + kcol;
#pragma unroll
    for (int kt = 0; kt < 16; ++kt)
#pragma unroll
        for (int r = 0; r < 4; ++r) {
            float val = c[kt][r] * inv[r];
            ap[(size_t)r * L_ + kt * 16] = val;
            P_lds[(size_t)(qrow4 + r) * PSTR + kcol + kt * 16] = f2bf(val);
        }
    __syncthreads();

    // PV: wave (qsub, dg=kq): O[16q][16d], K=1024
    int dg = kq;
    const u16* vb = vt + ((size_t)(n * H_ + h) * 64 + dg * 16 + lr) * L_;
    const u16* prow = &P_lds[(size_t)(qsub * 16 + lr) * PSTR];
    f32x4 acc = (f32x4){0.f, 0.f, 0.f, 0.f};
#pragma unroll
    for (int ks = 0; ks < 32; ++ks) {
        b16x8 a = *(const b16x8*)&prow[ks * 32 + lg * 8];
        b16x8 b = *(const b16x8*)&vb[ks * 32 + lg * 8];
        acc = __builtin_amdgcn_mfma_f32_16x16x32_bf16(a, b, acc, 0, 0, 0);
    }
#pragma unroll
    for (int r = 0; r < 4; ++r) {
        size_t q = (size_t)(n * L_ + q0 + qsub * 16 + lg * 4 + r);
        obf[q * D_ + h * 64 + dg * 16 + lr] = f2bf(acc[r]);
    }
}

// ---------- bf16 GEMM with fused epilogues ----------
// C[M,2048 or 1024] = [A0|A1h] @ Bw^T ; 128x128 tile, 4 waves, BK=64, dbuf gl_lds, swizzled.
// MODE 0: v+=bias[col]; (RELU); Cbf=bf16(v)          (o_proj, fc)
// MODE 1: col<1024: Cbf=bf16(sig(v)*xf); else Z=sig(v-bias[col&1023])   (rz gates)
// MODE 2: o=(1-z)*xf+z*tanh(v); outf=o; (WRH: Cbf=bf16(o))              (h gates)
template<int MODE, int RELU, int WRH>
__global__ __launch_bounds__(256) void gemm_fused_kernel(const u16* __restrict__ A0,
                                                         const u16* __restrict__ A1h,
                                                         const u16* __restrict__ Bw,
                                                         const float* __restrict__ bias,
                                                         const float* __restrict__ xf,
                                                         float* __restrict__ Z,
                                                         u16* __restrict__ Cbf,
                                                         float* __restrict__ outf,
                                                         int K) {
    __shared__ u16 As[2][128 * 64];
    __shared__ u16 Bs[2][128 * 64];
    int t = threadIdx.x, w = t >> 6, l = t & 63;
    int wr = w >> 1, wc = w & 1;
    int m0 = blockIdx.x * 128, n0 = blockIdx.y * 128;
    int fr = l & 15, fq = l >> 4;
    int srow = l >> 3;
    int gc8 = (l & 7) ^ (srow & 7);
    const u16* Bbase = Bw + (size_t)n0 * K;

    f32x4 acc[4][4];
#pragma unroll
    for (int i = 0; i < 4; ++i)
#pragma unroll
        for (int j = 0; j < 4; ++j) acc[i][j] = (f32x4){0.f, 0.f, 0.f, 0.f};

    auto STAGE = [&](int buf, int kk) {
        const u16* Asrc = (kk < 1024) ? A0 : A1h;
        int kc = kk & 1023;
#pragma unroll
        for (int i = 0; i < 4; ++i) {
            int r0 = (i * 4 + w) * 8;
            gl_lds16(&Asrc[(size_t)(m0 + r0 + srow) * 1024 + kc + gc8 * 8], &As[buf][r0 * 64]);
            gl_lds16(&Bbase[(size_t)(r0 + srow) * K + kk + gc8 * 8], &Bs[buf][r0 * 64]);
        }
    };
    STAGE(0, 0);
    const int NT = K >> 6;
    for (int kt = 0; kt < NT; ++kt) {
        int cur = kt & 1;
        if (kt + 1 < NT) {
            STAGE(cur ^ 1, (kt + 1) << 6);
            asm volatile("s_waitcnt vmcnt(8)" ::: "memory");
        } else {
            asm volatile("s_waitcnt vmcnt(0)" ::: "memory");
        }
        __builtin_amdgcn_s_barrier();
#pragma unroll
        for (int ks = 0; ks < 2; ++ks) {
            b16x8 af[4], bf[4];
#pragma unroll
            for (int i = 0; i < 4; ++i) {
                int row = wr * 64 + i * 16 + fr;
                af[i] = *(const b16x8*)&As[cur][row * 64 + (((ks * 4 + fq) ^ (fr & 7)) * 8)];
            }
#pragma unroll
            for (int j = 0; j < 4; ++j) {
                int row = wc * 64 + j * 16 + fr;
                bf[j] = *(const b16x8*)&Bs[cur][row * 64 + (((ks * 4 + fq) ^ (fr & 7)) * 8)];
            }
#pragma unroll
            for (int i = 0; i < 4; ++i)
#pragma unroll
                for (int j = 0; j < 4; ++j)
                    acc[i][j] = __builtin_amdgcn_mfma_f32_16x16x32_bf16(af[i], bf[j], acc[i][j], 0, 0, 0);
        }
        asm volatile("s_waitcnt lgkmcnt(0)" ::: "memory");
        __builtin_amdgcn_s_barrier();
    }
#pragma unroll
    for (int i = 0; i < 4; ++i) {
#pragma unroll
        for (int j = 0; j < 4; ++j) {
            int row = m0 + wr * 64 + i * 16 + fq * 4;
            int col = n0 + wc * 64 + j * 16 + fr;
            int c1 = col & 1023;
#pragma unroll
            for (int r = 0; r < 4; ++r) {
                float v = acc[i][j][r];
                size_t off = (size_t)(row + r) * 1024 + c1;
                if (MODE == 0) {
                    v += bias[col];
                    if (RELU) v = fmaxf(v, 0.f);
                    Cbf[off] = f2bf(v);
                } else if (MODE == 1) {
                    if (col < 1024) Cbf[off] = f2bf(sigmoidf_(v) * xf[off]);
                    else            Z[off] = sigmoidf_(v - bias[c1]);
                } else {
                    float z = Z[off];
                    float o = (1.f - z) * xf[off] + z * tanhf(v);
                    outf[off] = o;
                    if (WRH) Cbf[off] = f2bf(o);
                }
            }
        }
    }
}

extern "C" void kernel_launch(void* const* d_in, const int* in_sizes, int n_in,
                              void* d_out, int out_size, void* d_ws, size_t ws_size,
                              hipStream_t stream) {
    const float* value = (const float*)d_in[0];
    // d_in[1] = key (unused: reference sets k_ = normed value)
    const float* query = (const float*)d_in[2];
    const int* mask = (const int*)d_in[3];
    const float* wq = (const float*)d_in[4];
    const float* wk = (const float*)d_in[5];
    const float* wv = (const float*)d_in[6];
    const float* w_out = (const float*)d_in[7];
    const float* b_out = (const float*)d_in[8];
    const float* fc_w = (const float*)d_in[9];
    const float* fc_b = (const float*)d_in[10];
    const float* ln1_s = (const float*)d_in[11];
    const float* ln1_b = (const float*)d_in[12];
    const float* lnkv_s = (const float*)d_in[13];
    const float* lnkv_b = (const float*)d_in[14];
    const float* ln2_s = (const float*)d_in[15];
    const float* ln2_b = (const float*)d_in[16];
    const float* g1_W = (const float*)d_in[17];
    const float* g1_U = (const float*)d_in[18];
    const float* g1_bg = (const float*)d_in[19];
    const float* g2_W = (const float*)d_in[20];
    const float* g2_U = (const float*)d_in[21];
    const float* g2_bg = (const float*)d_in[22];

    float* out_f = (float*)d_out;                     // final out [4096][1024] fp32
    float* attn_f = out_f + MD_;                      // attn [N,H,L,L] fp32 (output 1)
    float* OutH = out_f;                              // h lives in out slice; h2 writes in place

    // ---- d_ws layout (u16 units) ----
    u16* WS = (u16*)d_ws;
    u16* Wop = WS;                                    // DD
    u16* Wfc = WS + (size_t)DD_;                      // DD
    u16* WQKV = WS + 2 * (size_t)DD_;                 // 16384
    u16* G1rz = WQKV + 16384;                         // 4DD
    u16* G1h  = G1rz + 4 * (size_t)DD_;               // 2DD
    u16* G2rz = G1h + 2 * (size_t)DD_;                // 4DD
    u16* G2h  = G2rz + 4 * (size_t)DD_;               // 2DD
    u16* Y    = G2h + 2 * (size_t)DD_;                // o_proj out
    u16* Xq   = Y + MD_;                              // query bf16
    u16* T1   = Xq + MD_;                             // t gate1 / reused t gate2
    u16* Hb   = T1 + MD_;                             // h bf16
    u16* F    = Hb + MD_;                             // fc out
    u16* QH   = F + MD_;
    u16* KH   = QH + MD_;
    u16* VT   = KH + MD_;
    u16* OBF  = VT + MD_;
    u16* LNQ  = OBF + MD_;
    u16* LNV  = LNQ + MD_;
    u16* LN2  = LNV + MD_;
    float* Z  = (float*)(LN2 + MD_);                  // z fp32 [4096][1024]

    dim3 grid_n1024(M_ / 128, 8);                     // 256 blocks
    dim3 grid_n2048(M_ / 128, 16);                    // 512 blocks

    // ---- weight prep ----
    prep_weights_kernel<<<7174, 256, 0, stream>>>(w_out, fc_w, wq, wk, wv,
                                                  g1_W, g1_U, g2_W, g2_U, WS);

    // ---- attention ----
    ln_kernel<<<M_, 256, 0, stream>>>(query, LNQ, ln1_s, ln1_b);
    ln_kernel<<<M_, 256, 0, stream>>>(value, LNV, lnkv_s, lnkv_b);
    proj_mfma_kernel<<<dim3(32, 16), 256, 0, stream>>>(LNQ, LNV, WQKV, QH, KH, VT);
    cvtq_kernel<<<M_ * D_ / 2048, 256, 0, stream>>>(query, Xq);
    qk_pv_kernel<<<dim3(L_ / 32, H_, N_), 512, 0, stream>>>(QH, KH, VT, mask, attn_f, OBF);
    // o_proj -> Y
    gemm_fused_kernel<0, 0, 0><<<grid_n1024, 256, 0, stream>>>(OBF, nullptr, Wop, b_out,
                                                               nullptr, nullptr, Y, nullptr, 1024);
    // GRU gate 1
    gemm_fused_kernel<1, 0, 0><<<grid_n2048, 256, 0, stream>>>(Y, Xq, G1rz, g1_bg,
                                                               query, Z, T1, nullptr, 2048);
    gemm_fused_kernel<2, 0, 1><<<grid_n1024, 256, 0, stream>>>(Y, T1, G1h, nullptr,
                                                               query, Z, Hb, OutH, 2048);
    // LN2 + FC
    ln_kernel<<<M_, 256, 0, stream>>>(OutH, LN2, ln2_s, ln2_b);
    gemm_fused_kernel<0, 1, 0><<<grid_n1024, 256, 0, stream>>>(LN2, nullptr, Wfc, fc_b,
                                                               nullptr, nullptr, F, nullptr, 1024);
    // GRU gate 2
    gemm_fused_kernel<1, 0, 0><<<grid_n2048, 256, 0, stream>>>(F, Hb, G2rz, g2_bg,
                                                               OutH, Z, T1, nullptr, 2048);
    gemm_fused_kernel<2, 0, 0><<<grid_n1024, 256, 0, stream>>>(F, T1, G2h, nullptr,
                                                               OutH, Z, nullptr, out_f, 2048);
}

// Round 9
// 401.652 us; speedup vs baseline: 5.8350x; 1.0983x over previous
//
#include <hip/hip_runtime.h>
#include <cstdint>
#include <cstddef>

#define N_ 4
#define L_ 1024
#define D_ 1024
#define H_ 16
#define HS_ 64
#define M_ (N_*L_)       // 4096 rows
#define DD_ (D_*D_)      // 1048576
#define MD_ ((size_t)M_*D_)

typedef unsigned short u16;
typedef __bf16 b16x8 __attribute__((ext_vector_type(8)));
typedef float f32x4 __attribute__((ext_vector_type(4)));

__device__ __forceinline__ float sigmoidf_(float x) { return 1.0f / (1.0f + __expf(-x)); }
__device__ __forceinline__ u16 f2bf(float f) {
    union { float f; uint32_t u; } c; c.f = f;
    uint32_t u = c.u;
    u += 0x7fffu + ((u >> 16) & 1u);   // RNE
    return (u16)(u >> 16);
}

// async global->LDS, 16B per lane
__device__ __forceinline__ void gl_lds16(const void* g, void* l) {
    auto gp = reinterpret_cast<const __attribute__((address_space(1))) unsigned int*>(
        reinterpret_cast<uintptr_t>(g));
    auto lp = reinterpret_cast<__attribute__((address_space(3))) unsigned int*>(
        reinterpret_cast<uintptr_t>(l));
    __builtin_amdgcn_global_load_lds(gp, lp, 16, 0, 0);
}

// ---------------- one-shot weight prep: all bf16 (incl. fused GRU layouts) ----------------
// ws0 layout (u16): Wop[DD] Wfc[DD] WQKV[16384] G1rz[4DD] G1h[2DD] G2rz[4DD] G2h[2DD]
__global__ __launch_bounds__(256) void prep_weights_kernel(
    const float* __restrict__ w_out, const float* __restrict__ fc_w,
    const float* __restrict__ wq, const float* __restrict__ wk, const float* __restrict__ wv,
    const float* __restrict__ g1W, const float* __restrict__ g1U,
    const float* __restrict__ g2W, const float* __restrict__ g2U,
    u16* __restrict__ ws0) {
    u16* Wop = ws0;
    u16* Wfc = ws0 + (size_t)DD_;
    u16* WQKV = ws0 + 2 * (size_t)DD_;
    u16* G1rz = WQKV + 16384;
    u16* G1h = G1rz + 4 * (size_t)DD_;
    u16* G2rz = G1h + 2 * (size_t)DD_;
    u16* G2h = G2rz + 4 * (size_t)DD_;
    int b = blockIdx.x, t = threadIdx.x;
    const float* src; u16* dst; size_t si, di;
    if (b < 512) {
        size_t f = (size_t)b * 2048 + t * 8; src = w_out; si = f; dst = Wop; di = f;
    } else if (b < 1024) {
        size_t f = (size_t)(b - 512) * 2048 + t * 8; src = fc_w; si = f; dst = Wfc; di = f;
    } else if (b < 1030) {
        size_t f = (size_t)(b - 1024) * 2048 + t * 8;
        int which = (int)(f >> 12); size_t off = f & 4095;
        src = which == 0 ? wq : (which == 1 ? wk : wv); si = off; dst = WQKV; di = f;
    } else if (b < 3078) {
        size_t f = (size_t)(b - 1030) * 2048 + t * 8;
        size_t row = f >> 11, k = f & 2047; size_t n2 = (row >= 1024) ? 1 : 0;
        src = (k < 1024) ? (g1W + n2 * DD_) : (g1U + n2 * DD_);
        si = (row & 1023) * 1024 + (k & 1023); dst = G1rz; di = f;
    } else if (b < 4102) {
        size_t f = (size_t)(b - 3078) * 2048 + t * 8;
        size_t row = f >> 11, k = f & 2047;
        src = (k < 1024) ? (g1W + 2 * (size_t)DD_) : (g1U + 2 * (size_t)DD_);
        si = row * 1024 + (k & 1023); dst = G1h; di = f;
    } else if (b < 6150) {
        size_t f = (size_t)(b - 4102) * 2048 + t * 8;
        size_t row = f >> 11, k = f & 2047; size_t n2 = (row >= 1024) ? 1 : 0;
        src = (k < 1024) ? (g2W + n2 * DD_) : (g2U + n2 * DD_);
        si = (row & 1023) * 1024 + (k & 1023); dst = G2rz; di = f;
    } else {
        size_t f = (size_t)(b - 6150) * 2048 + t * 8;
        size_t row = f >> 11, k = f & 2047;
        src = (k < 1024) ? (g2W + 2 * (size_t)DD_) : (g2U + 2 * (size_t)DD_);
        si = row * 1024 + (k & 1023); dst = G2h; di = f;
    }
    float4 a = *(const float4*)&src[si];
    float4 b4 = *(const float4*)&src[si + 4];
    u16 o[8] = { f2bf(a.x), f2bf(a.y), f2bf(a.z), f2bf(a.w),
                 f2bf(b4.x), f2bf(b4.y), f2bf(b4.z), f2bf(b4.w) };
    *(uint4*)&dst[di] = *(uint4*)o;
}

// ---------------- LayerNorm -> bf16 ----------------
__global__ __launch_bounds__(256) void ln_kernel(const float* __restrict__ x, u16* __restrict__ y,
                                                 const float* __restrict__ sc, const float* __restrict__ bi) {
    int row = blockIdx.x;
    const float* xr = x + (size_t)row * D_;
    int t = threadIdx.x;
    float4 v = *(const float4*)&xr[t * 4];
    float s = v.x + v.y + v.z + v.w;
    float q = v.x * v.x + v.y * v.y + v.z * v.z + v.w * v.w;
#pragma unroll
    for (int o = 32; o > 0; o >>= 1) { s += __shfl_xor(s, o); q += __shfl_xor(q, o); }
    __shared__ float ss[4], sq[4];
    int w = t >> 6;
    if ((t & 63) == 0) { ss[w] = s; sq[w] = q; }
    __syncthreads();
    s = ss[0] + ss[1] + ss[2] + ss[3];
    q = sq[0] + sq[1] + sq[2] + sq[3];
    float mean = s * (1.0f / D_);
    float var = q * (1.0f / D_) - mean * mean;
    float inv = rsqrtf(var + 1e-5f);
    float4 sv = *(const float4*)&sc[t * 4];
    float4 bv = *(const float4*)&bi[t * 4];
    u16 ov[4] = { f2bf((v.x - mean) * inv * sv.x + bv.x),
                  f2bf((v.y - mean) * inv * sv.y + bv.y),
                  f2bf((v.z - mean) * inv * sv.z + bv.z),
                  f2bf((v.w - mean) * inv * sv.w + bv.w) };
    *(ushort4*)&y[(size_t)row * D_ + t * 4] = *(ushort4*)ov;
}

// ---------- query fp32 -> bf16 flat ----------
__global__ __launch_bounds__(256) void cvtq_kernel(const float* __restrict__ src, u16* __restrict__ dst) {
    size_t f = ((size_t)blockIdx.x * 256 + threadIdx.x) * 8;
    float4 a = *(const float4*)&src[f];
    float4 b = *(const float4*)&src[f + 4];
    u16 o[8] = { f2bf(a.x), f2bf(a.y), f2bf(a.z), f2bf(a.w),
                 f2bf(b.x), f2bf(b.y), f2bf(b.z), f2bf(b.w) };
    *(uint4*)&dst[f] = *(uint4*)o;
}

// -------- MFMA per-head projections: qh/kh row-major + vt transposed, all bf16 --------
__global__ __launch_bounds__(256) void proj_mfma_kernel(const u16* __restrict__ qbf,
                                                        const u16* __restrict__ vbf,
                                                        const u16* __restrict__ wqkv,
                                                        u16* __restrict__ qh, u16* __restrict__ kh,
                                                        u16* __restrict__ vt) {
    int t = threadIdx.x, w = t >> 6, l = t & 63;
    int lr = l & 15, lg = l >> 4;
    int rb = blockIdx.x, h = blockIdx.y;
    int n = rb >> 3, lbase = (rb & 7) * 128;
    const u16* wqp = wqkv;
    const u16* wkp = wqkv + 4096;
    const u16* wvp = wqkv + 8192;
    b16x8 wqf[4][2], wkf[4][2], wvf[4][2];
#pragma unroll
    for (int dt = 0; dt < 4; ++dt)
#pragma unroll
        for (int ks = 0; ks < 2; ++ks) {
            int a = (dt * 16 + lr) * 64 + ks * 32 + lg * 8;
            wqf[dt][ks] = *(const b16x8*)&wqp[a];
            wkf[dt][ks] = *(const b16x8*)&wkp[a];
            wvf[dt][ks] = *(const b16x8*)&wvp[a];
        }
#pragma unroll
    for (int rr = 0; rr < 2; ++rr) {
        int rt = w * 2 + rr;
        size_t grow = (size_t)(n * 1024 + lbase + rt * 16 + lr);
        b16x8 aq[2], av[2];
#pragma unroll
        for (int ks = 0; ks < 2; ++ks) {
            aq[ks] = *(const b16x8*)&qbf[grow * D_ + h * 64 + ks * 32 + lg * 8];
            av[ks] = *(const b16x8*)&vbf[grow * D_ + h * 64 + ks * 32 + lg * 8];
        }
#pragma unroll
        for (int dt = 0; dt < 4; ++dt) {
            f32x4 cq = (f32x4){0.f, 0.f, 0.f, 0.f};
            f32x4 ck = (f32x4){0.f, 0.f, 0.f, 0.f};
            f32x4 cv = (f32x4){0.f, 0.f, 0.f, 0.f};
            cq = __builtin_amdgcn_mfma_f32_16x16x32_bf16(aq[0], wqf[dt][0], cq, 0, 0, 0);
            cq = __builtin_amdgcn_mfma_f32_16x16x32_bf16(aq[1], wqf[dt][1], cq, 0, 0, 0);
            ck = __builtin_amdgcn_mfma_f32_16x16x32_bf16(av[0], wkf[dt][0], ck, 0, 0, 0);
            ck = __builtin_amdgcn_mfma_f32_16x16x32_bf16(av[1], wkf[dt][1], ck, 0, 0, 0);
            cv = __builtin_amdgcn_mfma_f32_16x16x32_bf16(wvf[dt][0], av[0], cv, 0, 0, 0);
            cv = __builtin_amdgcn_mfma_f32_16x16x32_bf16(wvf[dt][1], av[1], cv, 0, 0, 0);
#pragma unroll
            for (int r = 0; r < 4; ++r) {
                size_t orow = (size_t)(n * 1024 + lbase + rt * 16 + lg * 4 + r);
                qh[orow * D_ + h * 64 + dt * 16 + lr] = f2bf(cq[r]);
                kh[orow * D_ + h * 64 + dt * 16 + lr] = f2bf(ck[r]);
                vt[((size_t)(n * H_ + h) * 64 + dt * 16 + lg * 4 + r) * L_ + lbase + rt * 16 + lr] = f2bf(cv[r]);
            }
        }
    }
}

// -------- fused MFMA QK^T + softmax + PV: block = 32 q x full L, 8 waves --------
#define PSTR 1032
__global__ __launch_bounds__(512, 4) void qk_pv_kernel(const u16* __restrict__ qh,
                                                       const u16* __restrict__ kh,
                                                       const u16* __restrict__ vt,
                                                       const int* __restrict__ mask,
                                                       float* __restrict__ attn,
                                                       u16* __restrict__ obf) {
    __shared__ u16 P_lds[32 * PSTR];       // 66KB
    __shared__ float redA[32][4];
    __shared__ float redB[32][4];
    int t = threadIdx.x;
    int w = t >> 6, l = t & 63;
    int qsub = w & 1, kq = w >> 1;
    int q0 = blockIdx.x * 32;
    int h = blockIdx.y, n = blockIdx.z;
    int lr = l & 15, lg = l >> 4;

    size_t qrow = ((size_t)(n * L_ + q0 + qsub * 16 + lr) * H_ + h) * HS_;
    b16x8 aq0 = *(const b16x8*)&qh[qrow + lg * 8];
    b16x8 aq1 = *(const b16x8*)&qh[qrow + 32 + lg * 8];

    f32x4 c[16];
#pragma unroll
    for (int i = 0; i < 16; ++i) c[i] = (f32x4){0.f, 0.f, 0.f, 0.f};

    size_t kbase = ((size_t)(n * L_ + kq * 256 + lr) * H_ + h) * HS_ + lg * 8;
#pragma unroll
    for (int kt = 0; kt < 16; ++kt) {
        const u16* kp = &kh[kbase + (size_t)kt * 16 * D_];
        b16x8 bk0 = *(const b16x8*)&kp[0];
        b16x8 bk1 = *(const b16x8*)&kp[32];
        c[kt] = __builtin_amdgcn_mfma_f32_16x16x32_bf16(aq0, bk0, c[kt], 0, 0, 0);
        c[kt] = __builtin_amdgcn_mfma_f32_16x16x32_bf16(aq1, bk1, c[kt], 0, 0, 0);
    }

    const float scl = 0.03125f;   // 1/sqrt(1024)
    int kcol = kq * 256 + lr;
    float rowmax[4] = { -1e30f, -1e30f, -1e30f, -1e30f };
#pragma unroll
    for (int kt = 0; kt < 16; ++kt) {
        int mk = mask[n * L_ + kcol + kt * 16];
#pragma unroll
        for (int r = 0; r < 4; ++r) {
            float s = (mk != 0) ? c[kt][r] * scl : -1e20f;
            c[kt][r] = s;
            rowmax[r] = fmaxf(rowmax[r], s);
        }
    }
#pragma unroll
    for (int o = 8; o > 0; o >>= 1)
#pragma unroll
        for (int r = 0; r < 4; ++r) rowmax[r] = fmaxf(rowmax[r], __shfl_xor(rowmax[r], o));

    int qrow4 = qsub * 16 + lg * 4;
    if (lr == 0) {
#pragma unroll
        for (int r = 0; r < 4; ++r) redA[qrow4 + r][kq] = rowmax[r];
    }
    __syncthreads();
#pragma unroll
    for (int r = 0; r < 4; ++r)
        rowmax[r] = fmaxf(fmaxf(redA[qrow4 + r][0], redA[qrow4 + r][1]),
                          fmaxf(redA[qrow4 + r][2], redA[qrow4 + r][3]));
    float rowsum[4] = { 0.f, 0.f, 0.f, 0.f };
#pragma unroll
    for (int kt = 0; kt < 16; ++kt)
#pragma unroll
        for (int r = 0; r < 4; ++r) {
            float e = __expf(c[kt][r] - rowmax[r]);
            c[kt][r] = e;
            rowsum[r] += e;
        }
#pragma unroll
    for (int o = 8; o > 0; o >>= 1)
#pragma unroll
        for (int r = 0; r < 4; ++r) rowsum[r] += __shfl_xor(rowsum[r], o);
    if (lr == 0) {
#pragma unroll
        for (int r = 0; r < 4; ++r) redB[qrow4 + r][kq] = rowsum[r];
    }
    __syncthreads();
    float inv[4];
#pragma unroll
    for (int r = 0; r < 4; ++r)
        inv[r] = 1.0f / (redB[qrow4 + r][0] + redB[qrow4 + r][1] +
                         redB[qrow4 + r][2] + redB[qrow4 + r][3]);

    // write attn fp32 (mandatory output) + stage P bf16 into LDS
    float* ap = attn + ((size_t)((n * H_ + h) * L_) + q0 + qrow4) * L_ + kcol;
#pragma unroll
    for (int kt = 0; kt < 16; ++kt)
#pragma unroll
        for (int r = 0; r < 4; ++r) {
            float val = c[kt][r] * inv[r];
            ap[(size_t)r * L_ + kt * 16] = val;
            P_lds[(size_t)(qrow4 + r) * PSTR + kcol + kt * 16] = f2bf(val);
        }
    __syncthreads();

    // PV: wave (qsub, dg=kq): O[16q][16d], K=1024
    int dg = kq;
    const u16* vb = vt + ((size_t)(n * H_ + h) * 64 + dg * 16 + lr) * L_;
    const u16* prow = &P_lds[(size_t)(qsub * 16 + lr) * PSTR];
    f32x4 acc = (f32x4){0.f, 0.f, 0.f, 0.f};
#pragma unroll
    for (int ks = 0; ks < 32; ++ks) {
        b16x8 a = *(const b16x8*)&prow[ks * 32 + lg * 8];
        b16x8 b = *(const b16x8*)&vb[ks * 32 + lg * 8];
        acc = __builtin_amdgcn_mfma_f32_16x16x32_bf16(a, b, acc, 0, 0, 0);
    }
#pragma unroll
    for (int r = 0; r < 4; ++r) {
        size_t q = (size_t)(n * L_ + q0 + qsub * 16 + lg * 4 + r);
        obf[q * D_ + h * 64 + dg * 16 + lr] = f2bf(acc[r]);
    }
}

// ---------- bf16 GEMM with fused epilogues, 512 threads / 8 waves per 128x128 tile ----------
// Wave tile 32x64 (wr = w&3 rows, wc = w>>2 cols), acc 2x4. BK=64, dbuf gl_lds w16,
// counted vmcnt(4), XOR-swizzled LDS (both-sides involution).
// MODE 0: v+=bias[col]; (RELU); Cbf=bf16(v)          (o_proj, fc)
// MODE 1: col<1024: Cbf=bf16(sig(v)*xf); else Z=sig(v-bias[col&1023])   (rz gates)
// MODE 2: o=(1-z)*xf+z*tanh(v); outf=o; (WRH: Cbf=bf16(o))              (h gates)
template<int MODE, int RELU, int WRH>
__global__ __launch_bounds__(512, 4) void gemm_fused_kernel(const u16* __restrict__ A0,
                                                            const u16* __restrict__ A1h,
                                                            const u16* __restrict__ Bw,
                                                            const float* __restrict__ bias,
                                                            const float* __restrict__ xf,
                                                            float* __restrict__ Z,
                                                            u16* __restrict__ Cbf,
                                                            float* __restrict__ outf,
                                                            int K) {
    __shared__ u16 As[2][128 * 64];
    __shared__ u16 Bs[2][128 * 64];
    int t = threadIdx.x, w = t >> 6, l = t & 63;
    int wr = w & 3, wc = w >> 2;
    int m0 = blockIdx.x * 128, n0 = blockIdx.y * 128;
    int fr = l & 15, fq = l >> 4;
    int srow = l >> 3;
    int gc8 = (l & 7) ^ (srow & 7);      // pre-swizzled source col-group (involution)
    const u16* Bbase = Bw + (size_t)n0 * K;

    f32x4 acc[2][4];
#pragma unroll
    for (int i = 0; i < 2; ++i)
#pragma unroll
        for (int j = 0; j < 4; ++j) acc[i][j] = (f32x4){0.f, 0.f, 0.f, 0.f};

    auto STAGE = [&](int buf, int kk) {
        const u16* Asrc = (MODE == 0 || kk < 1024) ? A0 : A1h;
        int kc = kk & 1023;
#pragma unroll
        for (int i = 0; i < 2; ++i) {
            int r0 = (i * 8 + w) * 8;            // wave-uniform 8-row group
            gl_lds16(&Asrc[(size_t)(m0 + r0 + srow) * 1024 + kc + gc8 * 8], &As[buf][r0 * 64]);
            gl_lds16(&Bbase[(size_t)(r0 + srow) * K + kk + gc8 * 8], &Bs[buf][r0 * 64]);
        }
    };
    STAGE(0, 0);
    const int NT = K >> 6;
    for (int kt = 0; kt < NT; ++kt) {
        int cur = kt & 1;
        if (kt + 1 < NT) {
            STAGE(cur ^ 1, (kt + 1) << 6);
            asm volatile("s_waitcnt vmcnt(4)" ::: "memory");
        } else {
            asm volatile("s_waitcnt vmcnt(0)" ::: "memory");
        }
        __builtin_amdgcn_s_barrier();
#pragma unroll
        for (int ks = 0; ks < 2; ++ks) {
            b16x8 af[2], bf[4];
#pragma unroll
            for (int i = 0; i < 2; ++i) {
                int row = wr * 32 + i * 16 + fr;
                af[i] = *(const b16x8*)&As[cur][row * 64 + (((ks * 4 + fq) ^ (fr & 7)) * 8)];
            }
#pragma unroll
            for (int j = 0; j < 4; ++j) {
                int row = wc * 64 + j * 16 + fr;
                bf[j] = *(const b16x8*)&Bs[cur][row * 64 + (((ks * 4 + fq) ^ (fr & 7)) * 8)];
            }
#pragma unroll
            for (int i = 0; i < 2; ++i)
#pragma unroll
                for (int j = 0; j < 4; ++j)
                    acc[i][j] = __builtin_amdgcn_mfma_f32_16x16x32_bf16(af[i], bf[j], acc[i][j], 0, 0, 0);
        }
        asm volatile("s_waitcnt lgkmcnt(0)" ::: "memory");
        __builtin_amdgcn_s_barrier();
    }
#pragma unroll
    for (int i = 0; i < 2; ++i) {
#pragma unroll
        for (int j = 0; j < 4; ++j) {
            int row = m0 + wr * 32 + i * 16 + fq * 4;
            int col = n0 + wc * 64 + j * 16 + fr;
            int c1 = col & 1023;
#pragma unroll
            for (int r = 0; r < 4; ++r) {
                float v = acc[i][j][r];
                size_t off = (size_t)(row + r) * 1024 + c1;
                if (MODE == 0) {
                    v += bias[col];
                    if (RELU) v = fmaxf(v, 0.f);
                    Cbf[off] = f2bf(v);
                } else if (MODE == 1) {
                    if (col < 1024) Cbf[off] = f2bf(sigmoidf_(v) * xf[off]);
                    else            Z[off] = sigmoidf_(v - bias[c1]);
                } else {
                    float z = Z[off];
                    float o = (1.f - z) * xf[off] + z * tanhf(v);
                    outf[off] = o;
                    if (WRH) Cbf[off] = f2bf(o);
                }
            }
        }
    }
}

extern "C" void kernel_launch(void* const* d_in, const int* in_sizes, int n_in,
                              void* d_out, int out_size, void* d_ws, size_t ws_size,
                              hipStream_t stream) {
    const float* value = (const float*)d_in[0];
    // d_in[1] = key (unused: reference sets k_ = normed value)
    const float* query = (const float*)d_in[2];
    const int* mask = (const int*)d_in[3];
    const float* wq = (const float*)d_in[4];
    const float* wk = (const float*)d_in[5];
    const float* wv = (const float*)d_in[6];
    const float* w_out = (const float*)d_in[7];
    const float* b_out = (const float*)d_in[8];
    const float* fc_w = (const float*)d_in[9];
    const float* fc_b = (const float*)d_in[10];
    const float* ln1_s = (const float*)d_in[11];
    const float* ln1_b = (const float*)d_in[12];
    const float* lnkv_s = (const float*)d_in[13];
    const float* lnkv_b = (const float*)d_in[14];
    const float* ln2_s = (const float*)d_in[15];
    const float* ln2_b = (const float*)d_in[16];
    const float* g1_W = (const float*)d_in[17];
    const float* g1_U = (const float*)d_in[18];
    const float* g1_bg = (const float*)d_in[19];
    const float* g2_W = (const float*)d_in[20];
    const float* g2_U = (const float*)d_in[21];
    const float* g2_bg = (const float*)d_in[22];

    float* out_f = (float*)d_out;                     // final out [4096][1024] fp32
    float* attn_f = out_f + MD_;                      // attn [N,H,L,L] fp32 (output 1)
    float* OutH = out_f;                              // h lives in out slice; h2 writes in place

    // ---- d_ws layout (u16 units) ----
    u16* WS = (u16*)d_ws;
    u16* Wop = WS;                                    // DD
    u16* Wfc = WS + (size_t)DD_;                      // DD
    u16* WQKV = WS + 2 * (size_t)DD_;                 // 16384
    u16* G1rz = WQKV + 16384;                         // 4DD
    u16* G1h  = G1rz + 4 * (size_t)DD_;               // 2DD
    u16* G2rz = G1h + 2 * (size_t)DD_;                // 4DD
    u16* G2h  = G2rz + 4 * (size_t)DD_;               // 2DD
    u16* Y    = G2h + 2 * (size_t)DD_;                // o_proj out
    u16* Xq   = Y + MD_;                              // query bf16
    u16* T1   = Xq + MD_;                             // t gate1 / reused t gate2
    u16* Hb   = T1 + MD_;                             // h bf16
    u16* F    = Hb + MD_;                             // fc out
    u16* QH   = F + MD_;
    u16* KH   = QH + MD_;
    u16* VT   = KH + MD_;
    u16* OBF  = VT + MD_;
    u16* LNQ  = OBF + MD_;
    u16* LNV  = LNQ + MD_;
    u16* LN2  = LNV + MD_;
    float* Z  = (float*)(LN2 + MD_);                  // z fp32 [4096][1024]

    dim3 grid_n1024(M_ / 128, 8);                     // 256 blocks
    dim3 grid_n2048(M_ / 128, 16);                    // 512 blocks

    // ---- weight prep ----
    prep_weights_kernel<<<7174, 256, 0, stream>>>(w_out, fc_w, wq, wk, wv,
                                                  g1_W, g1_U, g2_W, g2_U, WS);

    // ---- attention ----
    ln_kernel<<<M_, 256, 0, stream>>>(query, LNQ, ln1_s, ln1_b);
    ln_kernel<<<M_, 256, 0, stream>>>(value, LNV, lnkv_s, lnkv_b);
    proj_mfma_kernel<<<dim3(32, 16), 256, 0, stream>>>(LNQ, LNV, WQKV, QH, KH, VT);
    cvtq_kernel<<<M_ * D_ / 2048, 256, 0, stream>>>(query, Xq);
    qk_pv_kernel<<<dim3(L_ / 32, H_, N_), 512, 0, stream>>>(QH, KH, VT, mask, attn_f, OBF);
    // o_proj -> Y
    gemm_fused_kernel<0, 0, 0><<<grid_n1024, 512, 0, stream>>>(OBF, nullptr, Wop, b_out,
                                                               nullptr, nullptr, Y, nullptr, 1024);
    // GRU gate 1
    gemm_fused_kernel<1, 0, 0><<<grid_n2048, 512, 0, stream>>>(Y, Xq, G1rz, g1_bg,
                                                               query, Z, T1, nullptr, 2048);
    gemm_fused_kernel<2, 0, 1><<<grid_n1024, 512, 0, stream>>>(Y, T1, G1h, nullptr,
                                                               query, Z, Hb, OutH, 2048);
    // LN2 + FC
    ln_kernel<<<M_, 256, 0, stream>>>(OutH, LN2, ln2_s, ln2_b);
    gemm_fused_kernel<0, 1, 0><<<grid_n1024, 512, 0, stream>>>(LN2, nullptr, Wfc, fc_b,
                                                               nullptr, nullptr, F, nullptr, 1024);
    // GRU gate 2
    gemm_fused_kernel<1, 0, 0><<<grid_n2048, 512, 0, stream>>>(F, Hb, G2rz, g2_bg,
                                                               OutH, Z, T1, nullptr, 2048);
    gemm_fused_kernel<2, 0, 0><<<grid_n1024, 512, 0, stream>>>(F, T1, G2h, nullptr,
                                                               OutH, Z, nullptr, out_f, 2048);
}